// Round 4
// baseline (167.177 us; speedup 1.0000x reference)
//
#include <hip/hip_runtime.h>
#include <hip/hip_bf16.h>

// ChannelDeAttention: B=64,S=512,C=256,H=128,P=512
// bf16 MFMA (16x16x32), fp32 accum. 7 launches.

typedef __attribute__((ext_vector_type(8))) short bf16x8;
typedef __attribute__((ext_vector_type(4))) float f32x4;
typedef __attribute__((ext_vector_type(8))) unsigned short ushort8;

typedef __attribute__((address_space(1))) void* as1vp;
typedef __attribute__((address_space(3))) void* as3vp;

__device__ __forceinline__ void gl2lds16(const void* g, void* l) {
  __builtin_amdgcn_global_load_lds((as1vp)(void*)g, (as3vp)l, 16, 0, 0);
}

__device__ __forceinline__ float bf2f(unsigned short u) {
  union { unsigned int i; float f; } v; v.i = ((unsigned int)u) << 16; return v.f;
}
__device__ __forceinline__ unsigned short f2bf(float f) {
  union { float f; unsigned int i; } v; v.f = f;
  unsigned int r = v.i + 0x7FFFu + ((v.i >> 16) & 1u);
  return (unsigned short)(r >> 16);
}

// ---------------- transpose + fp32->bf16 cast: dst[c][r] = src[r][c] ----------------
__global__ void __launch_bounds__(256) tcast(const float* __restrict__ src,
                                             unsigned short* __restrict__ dst,
                                             int R, int Cc) {
  __shared__ float lds[64][65];
  const int t = threadIdx.x;
  const long bz = blockIdx.z;
  const int r0 = blockIdx.x * 64, c0 = blockIdx.y * 64;
  const float* S = src + bz * (long)R * Cc;
  unsigned short* D = dst + bz * (long)R * Cc;
  const int c = t & 63, rbase = (t >> 6) * 16;
#pragma unroll
  for (int i = 0; i < 16; ++i)
    lds[rbase + i][c] = S[(long)(r0 + rbase + i) * Cc + c0 + c];
  __syncthreads();
  const int rr = (t & 31) * 2, ccb = t >> 5;
#pragma unroll
  for (int j = 0; j < 8; ++j) {
    int cc = ccb + j * 8;
    unsigned int u0 = f2bf(lds[rr][cc]);
    unsigned int u1 = f2bf(lds[rr + 1][cc]);
    *(unsigned int*)(D + (long)(c0 + cc) * R + r0 + rr) = u0 | (u1 << 16);
  }
}

// --------- all weight transposes in one launch (184 tile descriptors) ---------------
__global__ void __launch_bounds__(256) tcast_w(
    const float* __restrict__ wq1, const float* __restrict__ wk1,
    const float* __restrict__ wq2, const float* __restrict__ wk2,
    const float* __restrict__ wq3, const float* __restrict__ wk3,
    const float* __restrict__ wv, const float* __restrict__ wo,
    unsigned short* __restrict__ W1, unsigned short* __restrict__ W2,
    unsigned short* __restrict__ W3, unsigned short* __restrict__ WV,
    unsigned short* __restrict__ WO) {
  __shared__ float lds[64][65];
  const int bid = blockIdx.x;
  const float* S; unsigned short* D; int R, Cc, r0, c0, rowoff = 0;
  if (bid < 32) {
    int m = bid >> 4, i = bid & 15;
    S = m ? wk1 : wq1; D = W1; R = 512; Cc = 128;
    r0 = (i & 7) * 64; c0 = (i >> 3) * 64; rowoff = m * 128;
  } else if (bid < 48) {
    int m = (bid - 32) >> 3, i = (bid - 32) & 7;
    S = m ? wk2 : wq2; D = W2; R = 256; Cc = 128;
    r0 = (i & 3) * 64; c0 = (i >> 2) * 64; rowoff = m * 128;
  } else if (bid < 56) {
    int m = (bid - 48) >> 2, i = (bid - 48) & 3;
    S = m ? wk3 : wq3; D = W3; R = 128; Cc = 128;
    r0 = (i & 1) * 64; c0 = (i >> 1) * 64; rowoff = m * 128;
  } else if (bid < 120) {
    int i = bid - 56; S = wv; D = WV; R = 512; Cc = 512;
    r0 = (i & 7) * 64; c0 = (i >> 3) * 64;
  } else {
    int i = bid - 120; S = wo; D = WO; R = 512; Cc = 512;
    r0 = (i & 7) * 64; c0 = (i >> 3) * 64;
  }
  const int t = threadIdx.x;
  const int c = t & 63, rbase = (t >> 6) * 16;
#pragma unroll
  for (int i = 0; i < 16; ++i)
    lds[rbase + i][c] = S[(long)(r0 + rbase + i) * Cc + c0 + c];
  __syncthreads();
  const int rr = (t & 31) * 2, ccb = t >> 5;
#pragma unroll
  for (int j = 0; j < 8; ++j) {
    int cc = ccb + j * 8;
    unsigned int u0 = f2bf(lds[rr][cc]);
    unsigned int u1 = f2bf(lds[rr + 1][cc]);
    *(unsigned int*)(D + (long)(c0 + cc + rowoff) * R + r0 + rr) = u0 | (u1 << 16);
  }
}

// ---------------- fused Q/K projections, BN=256 (full output width) -----------------
// grid (1,2,448): z<64 scale1(K=512), z<192 scale2(K=256), else scale3(K=128)
__global__ void __launch_bounds__(256) proj_all(
    const unsigned short* __restrict__ XT,
    const unsigned short* __restrict__ W1, const unsigned short* __restrict__ W2,
    const unsigned short* __restrict__ W3,
    unsigned short* __restrict__ Q1, unsigned short* __restrict__ Q2,
    unsigned short* __restrict__ Q3,
    const float* __restrict__ bq1, const float* __restrict__ bk1,
    const float* __restrict__ bq2, const float* __restrict__ bk2,
    const float* __restrict__ bq3, const float* __restrict__ bk3) {
  extern __shared__ char smem[];
  unsigned short* As = (unsigned short*)smem;            // [128][64]
  unsigned short* Bs = (unsigned short*)(smem + 16384);  // [256][64]
  const int z = blockIdx.z;
  const unsigned short* Ab; const unsigned short* Bw; unsigned short* O;
  const float *bq, *bk; int K;
  if (z < 64) {
    K = 512; Bw = W1; O = Q1 + (long)z * 65536; bq = bq1; bk = bk1;
    Ab = XT + (long)z * 131072;
  } else if (z < 192) {
    int u = z - 64; K = 256; Bw = W2; O = Q2 + (long)u * 65536; bq = bq2; bk = bk2;
    Ab = XT + (long)(u >> 1) * 131072 + (u & 1) * 256;
  } else {
    int u = z - 192; K = 128; Bw = W3; O = Q3 + (long)u * 65536; bq = bq3; bk = bk3;
    Ab = XT + (long)(u >> 2) * 131072 + (u & 3) * 128;
  }
  const int t = threadIdx.x, lane = t & 63, wid = t >> 6;
  const int wm = (wid >> 1) * 64, wn = (wid & 1) * 128;
  const int m0 = blockIdx.y * 128;
  Ab += (long)m0 * 512;
  const int srow = t >> 3, scol = (t & 7) * 8;
  f32x4 acc[4][8] = {};
  for (int k0 = 0; k0 < K; k0 += 64) {
#pragma unroll
    for (int i = 0; i < 4; ++i)
      gl2lds16(Ab + (long)(i * 32 + srow) * 512 + k0 + scol, smem + i * 4096 + t * 16);
#pragma unroll
    for (int i = 0; i < 8; ++i)
      gl2lds16(Bw + (long)(i * 32 + srow) * K + k0 + scol, smem + 16384 + i * 4096 + t * 16);
    __syncthreads();
#pragma unroll
    for (int kk = 0; kk < 2; ++kk) {
      bf16x8 af[4], bfr[8];
#pragma unroll
      for (int mi = 0; mi < 4; ++mi)
        af[mi] = *(const bf16x8*)(As + (wm + mi * 16 + (lane & 15)) * 64 + kk * 32 + (lane >> 4) * 8);
#pragma unroll
      for (int ni = 0; ni < 8; ++ni)
        bfr[ni] = *(const bf16x8*)(Bs + (wn + ni * 16 + (lane & 15)) * 64 + kk * 32 + (lane >> 4) * 8);
#pragma unroll
      for (int mi = 0; mi < 4; ++mi)
#pragma unroll
        for (int ni = 0; ni < 8; ++ni)
          acc[mi][ni] = __builtin_amdgcn_mfma_f32_16x16x32_bf16(af[mi], bfr[ni], acc[mi][ni], 0, 0, 0);
    }
    __syncthreads();
  }
#pragma unroll
  for (int ni = 0; ni < 8; ++ni) {
    int colL = wn + ni * 16 + (lane & 15);
    float bv_ = (colL < 128) ? bq[colL] : bk[colL - 128];
#pragma unroll
    for (int mi = 0; mi < 4; ++mi) {
      int rowb = m0 + wm + mi * 16 + (lane >> 4) * 4;
#pragma unroll
      for (int r = 0; r < 4; ++r)
        O[(long)(rowb + r) * 256 + colL] = f2bf(acc[mi][ni][r] + bv_);
    }
  }
}

// ------- pass A: scales 2+3 scores + softmax + sub-batch mean, swizzled LDS ---------
// grid 512: bid<256 -> scale3 (NS=4), else scale2 (NS=2). b = (bid&~255?u:bid)>>2, m0=(&3)*64
__global__ void __launch_bounds__(256) scores_mean(
    const unsigned short* __restrict__ QK2, const unsigned short* __restrict__ QK3,
    unsigned short* __restrict__ A2P, unsigned short* __restrict__ A3P) {
  __shared__ unsigned short Qs[64 * 64];    // swizzled
  __shared__ unsigned short Ks[256 * 64];   // swizzled
  const int bid = blockIdx.x;
  const unsigned short* QK; unsigned short* Aout; int NS, b, m0;
  if (bid < 256) { NS = 4; b = bid >> 2; m0 = (bid & 3) * 64; QK = QK3; Aout = A3P; }
  else { int u = bid - 256; NS = 2; b = u >> 2; m0 = (u & 3) * 64; QK = QK2; Aout = A2P; }
  const int t = threadIdx.x, lane = t & 63, w = t >> 6;
  const int r8 = t >> 3, sl = t & 7;
  const float sc = 0.088388347648318447f;
  const float invNS = 1.0f / NS;
  f32x4 avg[16] = {};
  for (int h = 0; h < NS; ++h) {
    const unsigned short* base = QK + ((long)(b * NS + h) << 16);
    f32x4 acc[16] = {};
    for (int kc = 0; kc < 2; ++kc) {
#pragma unroll
      for (int i = 0; i < 2; ++i) {
        int row = i * 32 + r8;
        gl2lds16(base + (long)(m0 + row) * 256 + kc * 64 + (sl ^ (row & 7)) * 8,
                 (char*)Qs + i * 4096 + t * 16);
      }
#pragma unroll
      for (int i = 0; i < 8; ++i) {
        int row = i * 32 + r8;
        gl2lds16(base + (long)row * 256 + 128 + kc * 64 + (sl ^ (row & 7)) * 8,
                 (char*)Ks + i * 4096 + t * 16);
      }
      __syncthreads();
#pragma unroll
      for (int kk = 0; kk < 2; ++kk) {
        const int qrow = w * 16 + (lane & 15);
        const int slot = kk * 4 + (lane >> 4);
        bf16x8 qf = *(const bf16x8*)((char*)Qs + qrow * 128 + 16 * (slot ^ (qrow & 7)));
#pragma unroll
        for (int ni = 0; ni < 16; ++ni) {
          int krow = ni * 16 + (lane & 15);
          bf16x8 kf = *(const bf16x8*)((char*)Ks + krow * 128 + 16 * (slot ^ (krow & 7)));
          acc[ni] = __builtin_amdgcn_mfma_f32_16x16x32_bf16(qf, kf, acc[ni], 0, 0, 0);
        }
      }
      __syncthreads();
    }
#pragma unroll
    for (int r = 0; r < 4; ++r) {
      float mx = -1e30f;
#pragma unroll
      for (int ni = 0; ni < 16; ++ni) mx = fmaxf(mx, acc[ni][r]);
#pragma unroll
      for (int off = 1; off < 16; off <<= 1) mx = fmaxf(mx, __shfl_xor(mx, off, 64));
      float s = 0.0f;
#pragma unroll
      for (int ni = 0; ni < 16; ++ni) {
        float p = __expf((acc[ni][r] - mx) * sc);
        acc[ni][r] = p;
        s += p;
      }
#pragma unroll
      for (int off = 1; off < 16; off <<= 1) s += __shfl_xor(s, off, 64);
      float f = invNS / s;
#pragma unroll
      for (int ni = 0; ni < 16; ++ni) avg[ni][r] += acc[ni][r] * f;
    }
  }
#pragma unroll
  for (int r = 0; r < 4; ++r) {
    int row = m0 + w * 16 + (lane >> 4) * 4 + r;
    unsigned short* Orow = Aout + ((long)b << 16) + (long)row * 256 + (lane & 15);
#pragma unroll
    for (int ni = 0; ni < 16; ++ni) Orow[ni * 16] = f2bf(avg[ni][r]);
  }
}

// ------- pass B: scale1 scores + softmax + gate combine -> ATTN ---------------------
// grid 256 (b*4 + m-tile)
__global__ void __launch_bounds__(256) scores1_gate(
    const unsigned short* __restrict__ QK1, const unsigned short* __restrict__ A2P,
    const unsigned short* __restrict__ A3P, unsigned short* __restrict__ ATTN) {
  __shared__ unsigned short Qs[64 * 64];
  __shared__ unsigned short Ks[256 * 64];
  const int bid = blockIdx.x;
  const int b = bid >> 2, m0 = (bid & 3) * 64;
  const unsigned short* base = QK1 + ((long)b << 16);
  const int t = threadIdx.x, lane = t & 63, w = t >> 6;
  const int r8 = t >> 3, sl = t & 7;
  f32x4 acc[16] = {};
  for (int kc = 0; kc < 2; ++kc) {
#pragma unroll
    for (int i = 0; i < 2; ++i) {
      int row = i * 32 + r8;
      gl2lds16(base + (long)(m0 + row) * 256 + kc * 64 + (sl ^ (row & 7)) * 8,
               (char*)Qs + i * 4096 + t * 16);
    }
#pragma unroll
    for (int i = 0; i < 8; ++i) {
      int row = i * 32 + r8;
      gl2lds16(base + (long)row * 256 + 128 + kc * 64 + (sl ^ (row & 7)) * 8,
               (char*)Ks + i * 4096 + t * 16);
    }
    __syncthreads();
#pragma unroll
    for (int kk = 0; kk < 2; ++kk) {
      const int qrow = w * 16 + (lane & 15);
      const int slot = kk * 4 + (lane >> 4);
      bf16x8 qf = *(const bf16x8*)((char*)Qs + qrow * 128 + 16 * (slot ^ (qrow & 7)));
#pragma unroll
      for (int ni = 0; ni < 16; ++ni) {
        int krow = ni * 16 + (lane & 15);
        bf16x8 kf = *(const bf16x8*)((char*)Ks + krow * 128 + 16 * (slot ^ (krow & 7)));
        acc[ni] = __builtin_amdgcn_mfma_f32_16x16x32_bf16(qf, kf, acc[ni], 0, 0, 0);
      }
    }
    __syncthreads();
  }
  const float sc = 0.088388347648318447f;
#pragma unroll
  for (int r = 0; r < 4; ++r) {
    float mx = -1e30f;
#pragma unroll
    for (int ni = 0; ni < 16; ++ni) mx = fmaxf(mx, acc[ni][r]);
#pragma unroll
    for (int off = 1; off < 16; off <<= 1) mx = fmaxf(mx, __shfl_xor(mx, off, 64));
    float s = 0.0f;
#pragma unroll
    for (int ni = 0; ni < 16; ++ni) {
      float p = __expf((acc[ni][r] - mx) * sc);
      acc[ni][r] = p;
      s += p;
    }
#pragma unroll
    for (int off = 1; off < 16; off <<= 1) s += __shfl_xor(s, off, 64);
    float inv = 1.0f / s;
    int row = m0 + w * 16 + (lane >> 4) * 4 + r;
    long roff = ((long)b << 16) + (long)row * 256 + (lane & 15);
#pragma unroll
    for (int ni = 0; ni < 16; ++ni) {
      long off = roff + ni * 16;
      float A1 = acc[ni][r] * inv;
      float A2 = bf2f(A2P[off]);
      float A3 = bf2f(A3P[off]);
      float m = fmaxf(A1, fmaxf(A2, A3));
      float e1 = __expf(A1 - m), e2 = __expf(A2 - m), e3 = __expf(A3 - m);
      ATTN[off] = f2bf((A1 * e1 + A2 * e2 + A3 * e3) / (e1 + e2 + e3));
    }
  }
}

// ---------------- generic NT GEMM, BN = NF*32 ---------------------------------------
template <int NF, int TRANS, int F32OUT, int BIAS>
__global__ void __launch_bounds__(256) gemm_nt(
    const unsigned short* __restrict__ A, const unsigned short* __restrict__ B,
    void* __restrict__ OutV, const float* __restrict__ bias,
    int lda, int ldb, int K, long astr, long bstr, long ostr, int ldo) {
  constexpr int BN = NF * 32;
  constexpr int NQ = (NF == 8) ? 2 : 1;
  extern __shared__ char smem[];
  unsigned short* As = (unsigned short*)smem;            // [128][64]
  unsigned short* Bs = (unsigned short*)(smem + 16384);  // [BN][64]
  const int t = threadIdx.x;
  const int lane = t & 63, wid = t >> 6;
  const int wm = (wid >> 1) * 64, wn = (wid & 1) * (NF * 16);
  const int m0 = blockIdx.y * 128, n0 = blockIdx.x * BN;
  const int bz = blockIdx.z;
  const unsigned short* Ab = A + (long)bz * astr + (long)m0 * lda;
  const unsigned short* Bb = B + (long)bz * bstr + (long)n0 * ldb;
  const int srow = t >> 3, scol = (t & 7) * 8;
  f32x4 acc[4][NF] = {};
  for (int k0 = 0; k0 < K; k0 += 64) {
#pragma unroll
    for (int i = 0; i < 4; ++i)
      gl2lds16(Ab + (long)(i * 32 + srow) * lda + k0 + scol, smem + i * 4096 + t * 16);
#pragma unroll
    for (int i = 0; i < BN / 32; ++i)
      gl2lds16(Bb + (long)(i * 32 + srow) * ldb + k0 + scol, smem + 16384 + i * 4096 + t * 16);
    __syncthreads();
#pragma unroll
    for (int kk = 0; kk < 2; ++kk) {
      bf16x8 af[4], bfr[NF];
#pragma unroll
      for (int mi = 0; mi < 4; ++mi)
        af[mi] = *(const bf16x8*)(As + (wm + mi * 16 + (lane & 15)) * 64 + kk * 32 + (lane >> 4) * 8);
#pragma unroll
      for (int ni = 0; ni < NF; ++ni)
        bfr[ni] = *(const bf16x8*)(Bs + (wn + ni * 16 + (lane & 15)) * 64 + kk * 32 + (lane >> 4) * 8);
#pragma unroll
      for (int mi = 0; mi < 4; ++mi)
#pragma unroll
        for (int ni = 0; ni < NF; ++ni)
          acc[mi][ni] = __builtin_amdgcn_mfma_f32_16x16x32_bf16(af[mi], bfr[ni], acc[mi][ni], 0, 0, 0);
    }
    __syncthreads();
  }
  if constexpr (!TRANS) {
    unsigned short* O = (unsigned short*)OutV + (long)bz * ostr;
#pragma unroll
    for (int ni = 0; ni < NF; ++ni) {
      int col = n0 + wn + ni * 16 + (lane & 15);
      float bv_ = BIAS ? bias[col] : 0.0f;
#pragma unroll
      for (int mi = 0; mi < 4; ++mi) {
        int rowb = m0 + wm + mi * 16 + (lane >> 4) * 4;
#pragma unroll
        for (int r = 0; r < 4; ++r)
          O[(long)(rowb + r) * ldo + col] = f2bf(acc[mi][ni][r] + bv_);
      }
    }
  } else {
    float* T = (float*)smem;
    const int LDT = 129;
#pragma unroll
    for (int p = 0; p < 2; ++p) {
#pragma unroll
      for (int q = 0; q < NQ; ++q) {
        bool fill = (wm == p * 64) && (NQ == 1 || wn == q * 128);
        if (fill) {
#pragma unroll
          for (int ni = 0; ni < NF; ++ni) {
            int colT = (NQ == 2) ? (ni * 16 + (lane & 15)) : (wn + ni * 16 + (lane & 15));
            float bv_ = BIAS ? bias[n0 + q * 128 + colT] : 0.0f;
#pragma unroll
            for (int mi = 0; mi < 4; ++mi)
#pragma unroll
              for (int r = 0; r < 4; ++r)
                T[(mi * 16 + (lane >> 4) * 4 + r) * LDT + colT] = acc[mi][ni][r] + bv_;
          }
        }
        __syncthreads();
        const int mloc = (t & 15) * 4;
#pragma unroll
        for (int j = 0; j < 8; ++j) {
          int n = j * 16 + (t >> 4);
          float v0 = T[(mloc + 0) * LDT + n];
          float v1 = T[(mloc + 1) * LDT + n];
          float v2 = T[(mloc + 2) * LDT + n];
          float v3 = T[(mloc + 3) * LDT + n];
          long orow = (long)(n0 + q * 128 + n) * ldo + m0 + p * 64 + mloc;
          if constexpr (F32OUT) {
            f32x4 vv = {v0, v1, v2, v3};
            *(f32x4*)((float*)OutV + (long)bz * ostr + orow) = vv;
          } else {
            unsigned long long pk = (unsigned long long)f2bf(v0) |
                                    ((unsigned long long)f2bf(v1) << 16) |
                                    ((unsigned long long)f2bf(v2) << 32) |
                                    ((unsigned long long)f2bf(v3) << 48);
            *(unsigned long long*)((unsigned short*)OutV + (long)bz * ostr + orow) = pk;
          }
        }
        __syncthreads();
      }
    }
  }
}

// ------------------------------------------------------------------------------------
extern "C" void kernel_launch(void* const* d_in, const int* in_sizes, int n_in,
                              void* d_out, int out_size, void* d_ws, size_t ws_size,
                              hipStream_t stream) {
  (void)in_sizes; (void)n_in; (void)out_size; (void)ws_size;
  const float* x   = (const float*)d_in[0];
  const float* wq1 = (const float*)d_in[1];
  const float* bq1 = (const float*)d_in[2];
  const float* wk1 = (const float*)d_in[3];
  const float* bk1 = (const float*)d_in[4];
  const float* wq2 = (const float*)d_in[5];
  const float* bq2 = (const float*)d_in[6];
  const float* wk2 = (const float*)d_in[7];
  const float* bk2 = (const float*)d_in[8];
  const float* wq3 = (const float*)d_in[9];
  const float* bq3 = (const float*)d_in[10];
  const float* wk3 = (const float*)d_in[11];
  const float* bk3 = (const float*)d_in[12];
  const float* wv  = (const float*)d_in[13];
  const float* bv  = (const float*)d_in[14];
  const float* wo  = (const float*)d_in[15];
  const float* bo  = (const float*)d_in[16];
  char* ws = (char*)d_ws;

  // workspace layout (bytes), peak 93,782,016
  unsigned short* XT   = (unsigned short*)(ws + 0);         // [64][256][512] 16.8MB
  unsigned short* WQK1 = (unsigned short*)(ws + 16777216);  // [256][512]
  unsigned short* WQK2 = (unsigned short*)(ws + 17039360);  // [256][256]
  unsigned short* WQK3 = (unsigned short*)(ws + 17170432);  // [256][128]
  unsigned short* WVT  = (unsigned short*)(ws + 17235968);  // [512][512]
  unsigned short* WOT  = (unsigned short*)(ws + 17760256);  // [512][512]
  unsigned short* QK1  = (unsigned short*)(ws + 18284544);  // [64][256][256]  (dead after passB)
  unsigned short* QK2  = (unsigned short*)(ws + 26673152);  // [128][256][256] (dead after passA)
  unsigned short* QK3  = (unsigned short*)(ws + 43450368);  // [256][256][256] (dead after passA)
  unsigned short* A2P  = (unsigned short*)(ws + 77004800);  // [64][256][256] averaged
  unsigned short* A3P  = (unsigned short*)(ws + 85393408);  // [64][256][256] averaged
  unsigned short* ATTN = (unsigned short*)(ws + 43450368);  // over dead QK3
  unsigned short* VT   = (unsigned short*)(ws + 51838976);  // over dead QK3 tail
  unsigned short* AV   = (unsigned short*)(ws + 18284544);  // over dead QK1/QK2

  dim3 blk(256);

  tcast<<<dim3(8, 4, 64), blk, 0, stream>>>(x, XT, 512, 256);
  tcast_w<<<dim3(184), blk, 0, stream>>>(wq1, wk1, wq2, wk2, wq3, wk3, wv, wo,
                                         WQK1, WQK2, WQK3, WVT, WOT);

  proj_all<<<dim3(1, 2, 448), blk, 49152, stream>>>(XT, WQK1, WQK2, WQK3, QK1, QK2, QK3,
                                                    bq1, bk1, bq2, bk2, bq3, bk3);

  scores_mean<<<dim3(512), blk, 0, stream>>>(QK2, QK3, A2P, A3P);
  scores1_gate<<<dim3(256), blk, 0, stream>>>(QK1, A2P, A3P, ATTN);

  // vT[b][s'][c] = (x^T wv + bv)^T  (TRANS store)
  gemm_nt<8, 1, 0, 1><<<dim3(2, 2, 64), blk, 49152, stream>>>(
      XT, WVT, VT, bv, 512, 512, 512, 131072, 0, 131072, 256);
  // av[c][s'] = attn @ v  (B^T = VT)
  gemm_nt<8, 0, 0, 0><<<dim3(2, 2, 64), blk, 49152, stream>>>(
      ATTN, VT, AV, nullptr, 256, 256, 256, 65536, 131072, 131072, 512);
  // out[b][p][c] = (av @ wo + bo)^T, fp32 (TRANS store)
  gemm_nt<8, 1, 1, 1><<<dim3(2, 2, 64), blk, 49152, stream>>>(
      AV, WOT, d_out, bo, 512, 512, 512, 131072, 0, 131072, 256);
}

// Round 5
// 135.480 us; speedup vs baseline: 1.2340x; 1.2340x over previous
//
#include <hip/hip_runtime.h>
#include <hip/hip_bf16.h>

// ChannelDeAttention: B=64,S=512,C=256,H=128,P=512
// bf16 MFMA (16x16x32), fp32 accum. 8 launches. All LDS tiles XOR-swizzled.

typedef __attribute__((ext_vector_type(8))) short bf16x8;
typedef __attribute__((ext_vector_type(4))) float f32x4;
typedef __attribute__((ext_vector_type(8))) unsigned short ushort8;

typedef __attribute__((address_space(1))) void* as1vp;
typedef __attribute__((address_space(3))) void* as3vp;

__device__ __forceinline__ void gl2lds16(const void* g, void* l) {
  __builtin_amdgcn_global_load_lds((as1vp)(void*)g, (as3vp)l, 16, 0, 0);
}

__device__ __forceinline__ float bf2f(unsigned short u) {
  union { unsigned int i; float f; } v; v.i = ((unsigned int)u) << 16; return v.f;
}
__device__ __forceinline__ unsigned short f2bf(float f) {
  union { float f; unsigned int i; } v; v.f = f;
  unsigned int r = v.i + 0x7FFFu + ((v.i >> 16) & 1u);
  return (unsigned short)(r >> 16);
}

// ---------------- transpose + fp32->bf16 cast: dst[c][r] = src[r][c] ----------------
__global__ void __launch_bounds__(256) tcast(const float* __restrict__ src,
                                             unsigned short* __restrict__ dst,
                                             int R, int Cc) {
  __shared__ float lds[64][65];
  const int t = threadIdx.x;
  const long bz = blockIdx.z;
  const int r0 = blockIdx.x * 64, c0 = blockIdx.y * 64;
  const float* S = src + bz * (long)R * Cc;
  unsigned short* D = dst + bz * (long)R * Cc;
  const int c = t & 63, rbase = (t >> 6) * 16;
#pragma unroll
  for (int i = 0; i < 16; ++i)
    lds[rbase + i][c] = S[(long)(r0 + rbase + i) * Cc + c0 + c];
  __syncthreads();
  const int rr = (t & 31) * 2, ccb = t >> 5;
#pragma unroll
  for (int j = 0; j < 8; ++j) {
    int cc = ccb + j * 8;
    unsigned int u0 = f2bf(lds[rr][cc]);
    unsigned int u1 = f2bf(lds[rr + 1][cc]);
    *(unsigned int*)(D + (long)(c0 + cc) * R + r0 + rr) = u0 | (u1 << 16);
  }
}

// --------- all weight transposes in one launch (184 tile descriptors) ---------------
__global__ void __launch_bounds__(256) tcast_w(
    const float* __restrict__ wq1, const float* __restrict__ wk1,
    const float* __restrict__ wq2, const float* __restrict__ wk2,
    const float* __restrict__ wq3, const float* __restrict__ wk3,
    const float* __restrict__ wv, const float* __restrict__ wo,
    unsigned short* __restrict__ W1, unsigned short* __restrict__ W2,
    unsigned short* __restrict__ W3, unsigned short* __restrict__ WV,
    unsigned short* __restrict__ WO) {
  __shared__ float lds[64][65];
  const int bid = blockIdx.x;
  const float* S; unsigned short* D; int R, Cc, r0, c0, rowoff = 0;
  if (bid < 32) {
    int m = bid >> 4, i = bid & 15;
    S = m ? wk1 : wq1; D = W1; R = 512; Cc = 128;
    r0 = (i & 7) * 64; c0 = (i >> 3) * 64; rowoff = m * 128;
  } else if (bid < 48) {
    int m = (bid - 32) >> 3, i = (bid - 32) & 7;
    S = m ? wk2 : wq2; D = W2; R = 256; Cc = 128;
    r0 = (i & 3) * 64; c0 = (i >> 2) * 64; rowoff = m * 128;
  } else if (bid < 56) {
    int m = (bid - 48) >> 2, i = (bid - 48) & 3;
    S = m ? wk3 : wq3; D = W3; R = 128; Cc = 128;
    r0 = (i & 1) * 64; c0 = (i >> 1) * 64; rowoff = m * 128;
  } else if (bid < 120) {
    int i = bid - 56; S = wv; D = WV; R = 512; Cc = 512;
    r0 = (i & 7) * 64; c0 = (i >> 3) * 64;
  } else {
    int i = bid - 120; S = wo; D = WO; R = 512; Cc = 512;
    r0 = (i & 7) * 64; c0 = (i >> 3) * 64;
  }
  const int t = threadIdx.x;
  const int c = t & 63, rbase = (t >> 6) * 16;
#pragma unroll
  for (int i = 0; i < 16; ++i)
    lds[rbase + i][c] = S[(long)(r0 + rbase + i) * Cc + c0 + c];
  __syncthreads();
  const int rr = (t & 31) * 2, ccb = t >> 5;
#pragma unroll
  for (int j = 0; j < 8; ++j) {
    int cc = ccb + j * 8;
    unsigned int u0 = f2bf(lds[rr][cc]);
    unsigned int u1 = f2bf(lds[rr + 1][cc]);
    *(unsigned int*)(D + (long)(c0 + cc + rowoff) * R + r0 + rr) = u0 | (u1 << 16);
  }
}

// ---------------- fused Q/K projections, BN=128, swizzled LDS -----------------------
// grid (2,2,448): z<64 scale1(K=512), z<192 scale2(K=256), else scale3(K=128)
__global__ void __launch_bounds__(256) proj_all(
    const unsigned short* __restrict__ XT,
    const unsigned short* __restrict__ W1, const unsigned short* __restrict__ W2,
    const unsigned short* __restrict__ W3,
    unsigned short* __restrict__ Q1, unsigned short* __restrict__ Q2,
    unsigned short* __restrict__ Q3,
    const float* __restrict__ bq1, const float* __restrict__ bk1,
    const float* __restrict__ bq2, const float* __restrict__ bk2,
    const float* __restrict__ bq3, const float* __restrict__ bk3) {
  extern __shared__ char smem[];
  const int z = blockIdx.z;
  const unsigned short* Ab; const unsigned short* Bw; unsigned short* O;
  const float *bq, *bk; int K;
  if (z < 64) {
    K = 512; Bw = W1; O = Q1 + (long)z * 65536; bq = bq1; bk = bk1;
    Ab = XT + (long)z * 131072;
  } else if (z < 192) {
    int u = z - 64; K = 256; Bw = W2; O = Q2 + (long)u * 65536; bq = bq2; bk = bk2;
    Ab = XT + (long)(u >> 1) * 131072 + (u & 1) * 256;
  } else {
    int u = z - 192; K = 128; Bw = W3; O = Q3 + (long)u * 65536; bq = bq3; bk = bk3;
    Ab = XT + (long)(u >> 2) * 131072 + (u & 3) * 128;
  }
  const int t = threadIdx.x, lane = t & 63, wid = t >> 6;
  const int wm = (wid >> 1) * 64, wn = (wid & 1) * 64;
  const int m0 = blockIdx.y * 128, n0 = blockIdx.x * 128;
  Ab += (long)m0 * 512;
  const unsigned short* Bb = Bw + (long)n0 * K;
  const int srow = t >> 3, ssl = t & 7;
  f32x4 acc[4][4] = {};
  for (int k0 = 0; k0 < K; k0 += 64) {
#pragma unroll
    for (int i = 0; i < 4; ++i) {
      int row = i * 32 + srow;
      int scol = (ssl ^ (row & 7)) * 8;
      gl2lds16(Ab + (long)row * 512 + k0 + scol, smem + i * 4096 + t * 16);
      gl2lds16(Bb + (long)row * K + k0 + scol, smem + 16384 + i * 4096 + t * 16);
    }
    __syncthreads();
#pragma unroll
    for (int kk = 0; kk < 2; ++kk) {
      const int slot = kk * 4 + (lane >> 4);
      bf16x8 af[4], bfr[4];
#pragma unroll
      for (int mi = 0; mi < 4; ++mi) {
        int row = wm + mi * 16 + (lane & 15);
        af[mi] = *(const bf16x8*)(smem + row * 128 + 16 * (slot ^ (row & 7)));
      }
#pragma unroll
      for (int ni = 0; ni < 4; ++ni) {
        int row = wn + ni * 16 + (lane & 15);
        bfr[ni] = *(const bf16x8*)(smem + 16384 + row * 128 + 16 * (slot ^ (row & 7)));
      }
#pragma unroll
      for (int mi = 0; mi < 4; ++mi)
#pragma unroll
        for (int ni = 0; ni < 4; ++ni)
          acc[mi][ni] = __builtin_amdgcn_mfma_f32_16x16x32_bf16(af[mi], bfr[ni], acc[mi][ni], 0, 0, 0);
    }
    __syncthreads();
  }
  const float* bias = (n0 == 0) ? bq : bk;
#pragma unroll
  for (int ni = 0; ni < 4; ++ni) {
    int colL = wn + ni * 16 + (lane & 15);
    float bv_ = bias[colL];
#pragma unroll
    for (int mi = 0; mi < 4; ++mi) {
      int rowb = m0 + wm + mi * 16 + (lane >> 4) * 4;
#pragma unroll
      for (int r = 0; r < 4; ++r)
        O[(long)(rowb + r) * 256 + n0 + colL] = f2bf(acc[mi][ni][r] + bv_);
    }
  }
}

// ------- pass A: scales 2+3 scores + softmax + sub-batch mean, swizzled LDS ---------
__global__ void __launch_bounds__(256) scores_mean(
    const unsigned short* __restrict__ QK2, const unsigned short* __restrict__ QK3,
    unsigned short* __restrict__ A2P, unsigned short* __restrict__ A3P) {
  __shared__ unsigned short Qs[64 * 64];
  __shared__ unsigned short Ks[256 * 64];
  const int bid = blockIdx.x;
  const unsigned short* QK; unsigned short* Aout; int NS, b, m0;
  if (bid < 256) { NS = 4; b = bid >> 2; m0 = (bid & 3) * 64; QK = QK3; Aout = A3P; }
  else { int u = bid - 256; NS = 2; b = u >> 2; m0 = (u & 3) * 64; QK = QK2; Aout = A2P; }
  const int t = threadIdx.x, lane = t & 63, w = t >> 6;
  const int r8 = t >> 3, sl = t & 7;
  const float sc = 0.088388347648318447f;
  const float invNS = 1.0f / NS;
  f32x4 avg[16] = {};
  for (int h = 0; h < NS; ++h) {
    const unsigned short* base = QK + ((long)(b * NS + h) << 16);
    f32x4 acc[16] = {};
    for (int kc = 0; kc < 2; ++kc) {
#pragma unroll
      for (int i = 0; i < 2; ++i) {
        int row = i * 32 + r8;
        gl2lds16(base + (long)(m0 + row) * 256 + kc * 64 + (sl ^ (row & 7)) * 8,
                 (char*)Qs + i * 4096 + t * 16);
      }
#pragma unroll
      for (int i = 0; i < 8; ++i) {
        int row = i * 32 + r8;
        gl2lds16(base + (long)row * 256 + 128 + kc * 64 + (sl ^ (row & 7)) * 8,
                 (char*)Ks + i * 4096 + t * 16);
      }
      __syncthreads();
#pragma unroll
      for (int kk = 0; kk < 2; ++kk) {
        const int qrow = w * 16 + (lane & 15);
        const int slot = kk * 4 + (lane >> 4);
        bf16x8 qf = *(const bf16x8*)((char*)Qs + qrow * 128 + 16 * (slot ^ (qrow & 7)));
#pragma unroll
        for (int ni = 0; ni < 16; ++ni) {
          int krow = ni * 16 + (lane & 15);
          bf16x8 kf = *(const bf16x8*)((char*)Ks + krow * 128 + 16 * (slot ^ (krow & 7)));
          acc[ni] = __builtin_amdgcn_mfma_f32_16x16x32_bf16(qf, kf, acc[ni], 0, 0, 0);
        }
      }
      __syncthreads();
    }
#pragma unroll
    for (int r = 0; r < 4; ++r) {
      float mx = -1e30f;
#pragma unroll
      for (int ni = 0; ni < 16; ++ni) mx = fmaxf(mx, acc[ni][r]);
#pragma unroll
      for (int off = 1; off < 16; off <<= 1) mx = fmaxf(mx, __shfl_xor(mx, off, 64));
      float s = 0.0f;
#pragma unroll
      for (int ni = 0; ni < 16; ++ni) {
        float p = __expf((acc[ni][r] - mx) * sc);
        acc[ni][r] = p;
        s += p;
      }
#pragma unroll
      for (int off = 1; off < 16; off <<= 1) s += __shfl_xor(s, off, 64);
      float f = invNS / s;
#pragma unroll
      for (int ni = 0; ni < 16; ++ni) avg[ni][r] += acc[ni][r] * f;
    }
  }
#pragma unroll
  for (int r = 0; r < 4; ++r) {
    int row = m0 + w * 16 + (lane >> 4) * 4 + r;
    unsigned short* Orow = Aout + ((long)b << 16) + (long)row * 256 + (lane & 15);
#pragma unroll
    for (int ni = 0; ni < 16; ++ni) Orow[ni * 16] = f2bf(avg[ni][r]);
  }
}

// ------- pass B: scale1 scores + softmax + gate combine -> ATTN ---------------------
__global__ void __launch_bounds__(256) scores1_gate(
    const unsigned short* __restrict__ QK1, const unsigned short* __restrict__ A2P,
    const unsigned short* __restrict__ A3P, unsigned short* __restrict__ ATTN) {
  __shared__ unsigned short Qs[64 * 64];
  __shared__ unsigned short Ks[256 * 64];
  const int bid = blockIdx.x;
  const int b = bid >> 2, m0 = (bid & 3) * 64;
  const unsigned short* base = QK1 + ((long)b << 16);
  const int t = threadIdx.x, lane = t & 63, w = t >> 6;
  const int r8 = t >> 3, sl = t & 7;
  f32x4 acc[16] = {};
  for (int kc = 0; kc < 2; ++kc) {
#pragma unroll
    for (int i = 0; i < 2; ++i) {
      int row = i * 32 + r8;
      gl2lds16(base + (long)(m0 + row) * 256 + kc * 64 + (sl ^ (row & 7)) * 8,
               (char*)Qs + i * 4096 + t * 16);
    }
#pragma unroll
    for (int i = 0; i < 8; ++i) {
      int row = i * 32 + r8;
      gl2lds16(base + (long)row * 256 + 128 + kc * 64 + (sl ^ (row & 7)) * 8,
               (char*)Ks + i * 4096 + t * 16);
    }
    __syncthreads();
#pragma unroll
    for (int kk = 0; kk < 2; ++kk) {
      const int qrow = w * 16 + (lane & 15);
      const int slot = kk * 4 + (lane >> 4);
      bf16x8 qf = *(const bf16x8*)((char*)Qs + qrow * 128 + 16 * (slot ^ (qrow & 7)));
#pragma unroll
      for (int ni = 0; ni < 16; ++ni) {
        int krow = ni * 16 + (lane & 15);
        bf16x8 kf = *(const bf16x8*)((char*)Ks + krow * 128 + 16 * (slot ^ (krow & 7)));
        acc[ni] = __builtin_amdgcn_mfma_f32_16x16x32_bf16(qf, kf, acc[ni], 0, 0, 0);
      }
    }
    __syncthreads();
  }
  const float sc = 0.088388347648318447f;
#pragma unroll
  for (int r = 0; r < 4; ++r) {
    float mx = -1e30f;
#pragma unroll
    for (int ni = 0; ni < 16; ++ni) mx = fmaxf(mx, acc[ni][r]);
#pragma unroll
    for (int off = 1; off < 16; off <<= 1) mx = fmaxf(mx, __shfl_xor(mx, off, 64));
    float s = 0.0f;
#pragma unroll
    for (int ni = 0; ni < 16; ++ni) {
      float p = __expf((acc[ni][r] - mx) * sc);
      acc[ni][r] = p;
      s += p;
    }
#pragma unroll
    for (int off = 1; off < 16; off <<= 1) s += __shfl_xor(s, off, 64);
    float inv = 1.0f / s;
    int row = m0 + w * 16 + (lane >> 4) * 4 + r;
    long roff = ((long)b << 16) + (long)row * 256 + (lane & 15);
#pragma unroll
    for (int ni = 0; ni < 16; ++ni) {
      long off = roff + ni * 16;
      float A1 = acc[ni][r] * inv;
      float A2 = bf2f(A2P[off]);
      float A3 = bf2f(A3P[off]);
      float m = fmaxf(A1, fmaxf(A2, A3));
      float e1 = __expf(A1 - m), e2 = __expf(A2 - m), e3 = __expf(A3 - m);
      ATTN[off] = f2bf((A1 * e1 + A2 * e2 + A3 * e3) / (e1 + e2 + e3));
    }
  }
}

// ---------------- generic NT GEMM, BN=128, swizzled LDS -----------------------------
template <int TRANS, int F32OUT, int BIAS>
__global__ void __launch_bounds__(256) gemm_nt(
    const unsigned short* __restrict__ A, const unsigned short* __restrict__ B,
    void* __restrict__ OutV, const float* __restrict__ bias,
    int lda, int ldb, int K, long astr, long bstr, long ostr, int ldo) {
  extern __shared__ char smem[];
  const int t = threadIdx.x;
  const int lane = t & 63, wid = t >> 6;
  const int wm = (wid >> 1) * 64, wn = (wid & 1) * 64;
  const int m0 = blockIdx.y * 128, n0 = blockIdx.x * 128;
  const int bz = blockIdx.z;
  const unsigned short* Ab = A + (long)bz * astr + (long)m0 * lda;
  const unsigned short* Bb = B + (long)bz * bstr + (long)n0 * ldb;
  const int srow = t >> 3, ssl = t & 7;
  f32x4 acc[4][4] = {};
  for (int k0 = 0; k0 < K; k0 += 64) {
#pragma unroll
    for (int i = 0; i < 4; ++i) {
      int row = i * 32 + srow;
      int scol = (ssl ^ (row & 7)) * 8;
      gl2lds16(Ab + (long)row * lda + k0 + scol, smem + i * 4096 + t * 16);
      gl2lds16(Bb + (long)row * ldb + k0 + scol, smem + 16384 + i * 4096 + t * 16);
    }
    __syncthreads();
#pragma unroll
    for (int kk = 0; kk < 2; ++kk) {
      const int slot = kk * 4 + (lane >> 4);
      bf16x8 af[4], bfr[4];
#pragma unroll
      for (int mi = 0; mi < 4; ++mi) {
        int row = wm + mi * 16 + (lane & 15);
        af[mi] = *(const bf16x8*)(smem + row * 128 + 16 * (slot ^ (row & 7)));
      }
#pragma unroll
      for (int ni = 0; ni < 4; ++ni) {
        int row = wn + ni * 16 + (lane & 15);
        bfr[ni] = *(const bf16x8*)(smem + 16384 + row * 128 + 16 * (slot ^ (row & 7)));
      }
#pragma unroll
      for (int mi = 0; mi < 4; ++mi)
#pragma unroll
        for (int ni = 0; ni < 4; ++ni)
          acc[mi][ni] = __builtin_amdgcn_mfma_f32_16x16x32_bf16(af[mi], bfr[ni], acc[mi][ni], 0, 0, 0);
    }
    __syncthreads();
  }
  if constexpr (!TRANS) {
    unsigned short* O = (unsigned short*)OutV + (long)bz * ostr;
#pragma unroll
    for (int ni = 0; ni < 4; ++ni) {
      int col = n0 + wn + ni * 16 + (lane & 15);
      float bv_ = BIAS ? bias[col] : 0.0f;
#pragma unroll
      for (int mi = 0; mi < 4; ++mi) {
        int rowb = m0 + wm + mi * 16 + (lane >> 4) * 4;
#pragma unroll
        for (int r = 0; r < 4; ++r)
          O[(long)(rowb + r) * ldo + col] = f2bf(acc[mi][ni][r] + bv_);
      }
    }
  } else {
    float* T = (float*)smem;
    const int LDT = 129;
#pragma unroll
    for (int p = 0; p < 2; ++p) {
      if (wm == p * 64) {
#pragma unroll
        for (int ni = 0; ni < 4; ++ni) {
          int colL = wn + ni * 16 + (lane & 15);
          float bv_ = BIAS ? bias[n0 + colL] : 0.0f;
#pragma unroll
          for (int mi = 0; mi < 4; ++mi)
#pragma unroll
            for (int r = 0; r < 4; ++r)
              T[(mi * 16 + (lane >> 4) * 4 + r) * LDT + colL] = acc[mi][ni][r] + bv_;
        }
      }
      __syncthreads();
      const int mloc = (t & 15) * 4;
#pragma unroll
      for (int j = 0; j < 8; ++j) {
        int n = j * 16 + (t >> 4);
        float v0 = T[(mloc + 0) * LDT + n];
        float v1 = T[(mloc + 1) * LDT + n];
        float v2 = T[(mloc + 2) * LDT + n];
        float v3 = T[(mloc + 3) * LDT + n];
        long orow = (long)(n0 + n) * ldo + m0 + p * 64 + mloc;
        if constexpr (F32OUT) {
          f32x4 vv = {v0, v1, v2, v3};
          *(f32x4*)((float*)OutV + (long)bz * ostr + orow) = vv;
        } else {
          unsigned long long pk = (unsigned long long)f2bf(v0) |
                                  ((unsigned long long)f2bf(v1) << 16) |
                                  ((unsigned long long)f2bf(v2) << 32) |
                                  ((unsigned long long)f2bf(v3) << 48);
          *(unsigned long long*)((unsigned short*)OutV + (long)bz * ostr + orow) = pk;
        }
      }
      __syncthreads();
    }
  }
}

// ------------------------------------------------------------------------------------
extern "C" void kernel_launch(void* const* d_in, const int* in_sizes, int n_in,
                              void* d_out, int out_size, void* d_ws, size_t ws_size,
                              hipStream_t stream) {
  (void)in_sizes; (void)n_in; (void)out_size; (void)ws_size;
  const float* x   = (const float*)d_in[0];
  const float* wq1 = (const float*)d_in[1];
  const float* bq1 = (const float*)d_in[2];
  const float* wk1 = (const float*)d_in[3];
  const float* bk1 = (const float*)d_in[4];
  const float* wq2 = (const float*)d_in[5];
  const float* bq2 = (const float*)d_in[6];
  const float* wk2 = (const float*)d_in[7];
  const float* bk2 = (const float*)d_in[8];
  const float* wq3 = (const float*)d_in[9];
  const float* bq3 = (const float*)d_in[10];
  const float* wk3 = (const float*)d_in[11];
  const float* bk3 = (const float*)d_in[12];
  const float* wv  = (const float*)d_in[13];
  const float* bv  = (const float*)d_in[14];
  const float* wo  = (const float*)d_in[15];
  const float* bo  = (const float*)d_in[16];
  char* ws = (char*)d_ws;

  // workspace layout (bytes), peak 93,782,016
  unsigned short* XT   = (unsigned short*)(ws + 0);         // [64][256][512] 16.8MB
  unsigned short* WQK1 = (unsigned short*)(ws + 16777216);  // [256][512]
  unsigned short* WQK2 = (unsigned short*)(ws + 17039360);  // [256][256]
  unsigned short* WQK3 = (unsigned short*)(ws + 17170432);  // [256][128]
  unsigned short* WVT  = (unsigned short*)(ws + 17235968);  // [512][512]
  unsigned short* WOT  = (unsigned short*)(ws + 17760256);  // [512][512]
  unsigned short* QK1  = (unsigned short*)(ws + 18284544);  // [64][256][256]  (dead after passB)
  unsigned short* QK2  = (unsigned short*)(ws + 26673152);  // [128][256][256] (dead after passA)
  unsigned short* QK3  = (unsigned short*)(ws + 43450368);  // [256][256][256] (dead after passA)
  unsigned short* A2P  = (unsigned short*)(ws + 77004800);  // [64][256][256] averaged
  unsigned short* A3P  = (unsigned short*)(ws + 85393408);  // [64][256][256] averaged
  unsigned short* ATTN = (unsigned short*)(ws + 43450368);  // over dead QK3
  unsigned short* VT   = (unsigned short*)(ws + 51838976);  // over dead QK3 tail
  unsigned short* AV   = (unsigned short*)(ws + 18284544);  // over dead QK1/QK2

  dim3 blk(256);

  tcast<<<dim3(8, 4, 64), blk, 0, stream>>>(x, XT, 512, 256);
  tcast_w<<<dim3(184), blk, 0, stream>>>(wq1, wk1, wq2, wk2, wq3, wk3, wv, wo,
                                         WQK1, WQK2, WQK3, WVT, WOT);

  proj_all<<<dim3(2, 2, 448), blk, 32768, stream>>>(XT, WQK1, WQK2, WQK3, QK1, QK2, QK3,
                                                    bq1, bk1, bq2, bk2, bq3, bk3);

  scores_mean<<<dim3(512), blk, 0, stream>>>(QK2, QK3, A2P, A3P);
  scores1_gate<<<dim3(256), blk, 0, stream>>>(QK1, A2P, A3P, ATTN);

  // vT[b][s'][c] = (x^T wv + bv)^T  (TRANS store)
  gemm_nt<1, 0, 1><<<dim3(4, 2, 64), blk, 33280, stream>>>(
      XT, WVT, VT, bv, 512, 512, 512, 131072, 0, 131072, 256);
  // av[c][s'] = attn @ v  (B^T = VT)
  gemm_nt<0, 0, 0><<<dim3(4, 2, 64), blk, 32768, stream>>>(
      ATTN, VT, AV, nullptr, 256, 256, 256, 65536, 131072, 131072, 512);
  // out[b][p][c] = (av @ wo + bo)^T, fp32 (TRANS store)
  gemm_nt<1, 1, 1><<<dim3(4, 2, 64), blk, 33280, stream>>>(
      AV, WOT, d_out, bo, 512, 512, 512, 131072, 0, 131072, 256);
}

// Round 6
// 132.449 us; speedup vs baseline: 1.2622x; 1.0229x over previous
//
#include <hip/hip_runtime.h>
#include <hip/hip_bf16.h>

// ChannelDeAttention: B=64,S=512,C=256,H=128,P=512
// bf16 MFMA (16x16x32), fp32 accum. 7 launches. All LDS XOR-swizzled.
// GEMMs: 8-wave blocks (512 thr), wave-tile 64x64, acc[4][4].

typedef __attribute__((ext_vector_type(8))) short bf16x8;
typedef __attribute__((ext_vector_type(4))) float f32x4;
typedef __attribute__((ext_vector_type(8))) unsigned short ushort8;

typedef __attribute__((address_space(1))) void* as1vp;
typedef __attribute__((address_space(3))) void* as3vp;

__device__ __forceinline__ void gl2lds16(const void* g, void* l) {
  __builtin_amdgcn_global_load_lds((as1vp)(void*)g, (as3vp)l, 16, 0, 0);
}

__device__ __forceinline__ float bf2f(unsigned short u) {
  union { unsigned int i; float f; } v; v.i = ((unsigned int)u) << 16; return v.f;
}
__device__ __forceinline__ unsigned short f2bf(float f) {
  union { float f; unsigned int i; } v; v.f = f;
  unsigned int r = v.i + 0x7FFFu + ((v.i >> 16) & 1u);
  return (unsigned short)(r >> 16);
}

// ------- all transposes (x + 8 weights) in one launch: dst[c][r] = src[r][c] --------
__global__ void __launch_bounds__(256) tcast_all(
    const float* __restrict__ x,
    const float* __restrict__ wq1, const float* __restrict__ wk1,
    const float* __restrict__ wq2, const float* __restrict__ wk2,
    const float* __restrict__ wq3, const float* __restrict__ wk3,
    const float* __restrict__ wv, const float* __restrict__ wo,
    unsigned short* __restrict__ XT,
    unsigned short* __restrict__ W1, unsigned short* __restrict__ W2,
    unsigned short* __restrict__ W3, unsigned short* __restrict__ WV,
    unsigned short* __restrict__ WO) {
  __shared__ float lds[64][65];
  const int bid = blockIdx.x;
  const float* S; unsigned short* D; int R, Cc, r0, c0, rowoff = 0;
  if (bid < 2048) {
    // x: [64][512][256] -> XT [64][256][512]; 32 tiles per batch
    int bz = bid >> 5, i = bid & 31;
    S = x + (long)bz * 131072; D = XT + (long)bz * 131072;
    R = 512; Cc = 256; r0 = (i & 7) * 64; c0 = (i >> 3) * 64;
  } else {
    int wb = bid - 2048;
    if (wb < 32) {
      int m = wb >> 4, i = wb & 15;
      S = m ? wk1 : wq1; D = W1; R = 512; Cc = 128;
      r0 = (i & 7) * 64; c0 = (i >> 3) * 64; rowoff = m * 128;
    } else if (wb < 48) {
      int m = (wb - 32) >> 3, i = (wb - 32) & 7;
      S = m ? wk2 : wq2; D = W2; R = 256; Cc = 128;
      r0 = (i & 3) * 64; c0 = (i >> 2) * 64; rowoff = m * 128;
    } else if (wb < 56) {
      int m = (wb - 48) >> 2, i = (wb - 48) & 3;
      S = m ? wk3 : wq3; D = W3; R = 128; Cc = 128;
      r0 = (i & 1) * 64; c0 = (i >> 1) * 64; rowoff = m * 128;
    } else if (wb < 120) {
      int i = wb - 56; S = wv; D = WV; R = 512; Cc = 512;
      r0 = (i & 7) * 64; c0 = (i >> 3) * 64;
    } else {
      int i = wb - 120; S = wo; D = WO; R = 512; Cc = 512;
      r0 = (i & 7) * 64; c0 = (i >> 3) * 64;
    }
  }
  const int t = threadIdx.x;
  const int c = t & 63, rbase = (t >> 6) * 16;
#pragma unroll
  for (int i = 0; i < 16; ++i)
    lds[rbase + i][c] = S[(long)(r0 + rbase + i) * Cc + c0 + c];
  __syncthreads();
  const int rr = (t & 31) * 2, ccb = t >> 5;
#pragma unroll
  for (int j = 0; j < 8; ++j) {
    int cc = ccb + j * 8;
    unsigned int u0 = f2bf(lds[rr][cc]);
    unsigned int u1 = f2bf(lds[rr + 1][cc]);
    *(unsigned int*)(D + (long)(c0 + cc + rowoff) * R + r0 + rr) = u0 | (u1 << 16);
  }
}

// ------- fused Q/K projections, 8 waves, BM=128 BN=256 (full width), swizzled -------
// grid (1,2,448): z<64 scale1(K=512), z<192 scale2(K=256), else scale3(K=128)
__global__ void __launch_bounds__(512) proj_all8(
    const unsigned short* __restrict__ XT,
    const unsigned short* __restrict__ W1, const unsigned short* __restrict__ W2,
    const unsigned short* __restrict__ W3,
    unsigned short* __restrict__ Q1, unsigned short* __restrict__ Q2,
    unsigned short* __restrict__ Q3,
    const float* __restrict__ bq1, const float* __restrict__ bk1,
    const float* __restrict__ bq2, const float* __restrict__ bk2,
    const float* __restrict__ bq3, const float* __restrict__ bk3) {
  extern __shared__ char smem[];  // A [128][64]sw 16K, B [256][64]sw 32K
  const int z = blockIdx.z;
  const unsigned short* Ab; const unsigned short* Bw; unsigned short* O;
  const float *bq, *bk; int K;
  if (z < 64) {
    K = 512; Bw = W1; O = Q1 + (long)z * 65536; bq = bq1; bk = bk1;
    Ab = XT + (long)z * 131072;
  } else if (z < 192) {
    int u = z - 64; K = 256; Bw = W2; O = Q2 + (long)u * 65536; bq = bq2; bk = bk2;
    Ab = XT + (long)(u >> 1) * 131072 + (u & 1) * 256;
  } else {
    int u = z - 192; K = 128; Bw = W3; O = Q3 + (long)u * 65536; bq = bq3; bk = bk3;
    Ab = XT + (long)(u >> 2) * 131072 + (u & 3) * 128;
  }
  const int t = threadIdx.x, lane = t & 63, wid = t >> 6;
  const int wmb = (wid >> 2) * 64, wnb = (wid & 3) * 64;  // 2m x 4n waves
  const int m0 = blockIdx.y * 128;
  Ab += (long)m0 * 512;
  const int srow = t >> 3, ssl = t & 7;
  f32x4 acc[4][4] = {};
  for (int k0 = 0; k0 < K; k0 += 64) {
#pragma unroll
    for (int i = 0; i < 2; ++i) {
      int row = i * 64 + srow;
      gl2lds16(Ab + (long)row * 512 + k0 + (ssl ^ (row & 7)) * 8, smem + i * 8192 + t * 16);
    }
#pragma unroll
    for (int i = 0; i < 4; ++i) {
      int row = i * 64 + srow;
      gl2lds16(Bw + (long)row * K + k0 + (ssl ^ (row & 7)) * 8, smem + 16384 + i * 8192 + t * 16);
    }
    __syncthreads();
#pragma unroll
    for (int kk = 0; kk < 2; ++kk) {
      const int slot = kk * 4 + (lane >> 4);
      bf16x8 af[4], bfr[4];
#pragma unroll
      for (int mi = 0; mi < 4; ++mi) {
        int row = wmb + mi * 16 + (lane & 15);
        af[mi] = *(const bf16x8*)(smem + row * 128 + 16 * (slot ^ (row & 7)));
      }
#pragma unroll
      for (int ni = 0; ni < 4; ++ni) {
        int row = wnb + ni * 16 + (lane & 15);
        bfr[ni] = *(const bf16x8*)(smem + 16384 + row * 128 + 16 * (slot ^ (row & 7)));
      }
#pragma unroll
      for (int mi = 0; mi < 4; ++mi)
#pragma unroll
        for (int ni = 0; ni < 4; ++ni)
          acc[mi][ni] = __builtin_amdgcn_mfma_f32_16x16x32_bf16(af[mi], bfr[ni], acc[mi][ni], 0, 0, 0);
    }
    __syncthreads();
  }
#pragma unroll
  for (int ni = 0; ni < 4; ++ni) {
    int colL = wnb + ni * 16 + (lane & 15);
    float bv_ = (colL < 128) ? bq[colL] : bk[colL - 128];
#pragma unroll
    for (int mi = 0; mi < 4; ++mi) {
      int rowb = m0 + wmb + mi * 16 + (lane >> 4) * 4;
#pragma unroll
      for (int r = 0; r < 4; ++r)
        O[(long)(rowb + r) * 256 + colL] = f2bf(acc[mi][ni][r] + bv_);
    }
  }
}

// ------- pass A: scales 2+3 scores + softmax + sub-batch mean -----------------------
// output in FRAGMENT layout: buf[((b*4+m0idx)*256 + t)*64 + r*16 + ni]
__global__ void __launch_bounds__(256) scores_mean(
    const unsigned short* __restrict__ QK2, const unsigned short* __restrict__ QK3,
    unsigned short* __restrict__ A2P, unsigned short* __restrict__ A3P) {
  __shared__ unsigned short Qs[64 * 64];
  __shared__ unsigned short Ks[256 * 64];
  const int bid = blockIdx.x;
  const unsigned short* QK; unsigned short* Aout; int NS, b, m0idx;
  if (bid < 256) { NS = 4; b = bid >> 2; m0idx = bid & 3; QK = QK3; Aout = A3P; }
  else { int u = bid - 256; NS = 2; b = u >> 2; m0idx = u & 3; QK = QK2; Aout = A2P; }
  const int m0 = m0idx * 64;
  const int t = threadIdx.x, lane = t & 63, w = t >> 6;
  const int r8 = t >> 3, sl = t & 7;
  const float sc = 0.088388347648318447f;
  const float invNS = 1.0f / NS;
  f32x4 avg[16] = {};
  for (int h = 0; h < NS; ++h) {
    const unsigned short* base = QK + ((long)(b * NS + h) << 16);
    f32x4 acc[16] = {};
    for (int kc = 0; kc < 2; ++kc) {
#pragma unroll
      for (int i = 0; i < 2; ++i) {
        int row = i * 32 + r8;
        gl2lds16(base + (long)(m0 + row) * 256 + kc * 64 + (sl ^ (row & 7)) * 8,
                 (char*)Qs + i * 4096 + t * 16);
      }
#pragma unroll
      for (int i = 0; i < 8; ++i) {
        int row = i * 32 + r8;
        gl2lds16(base + (long)row * 256 + 128 + kc * 64 + (sl ^ (row & 7)) * 8,
                 (char*)Ks + i * 4096 + t * 16);
      }
      __syncthreads();
#pragma unroll
      for (int kk = 0; kk < 2; ++kk) {
        const int qrow = w * 16 + (lane & 15);
        const int slot = kk * 4 + (lane >> 4);
        bf16x8 qf = *(const bf16x8*)((char*)Qs + qrow * 128 + 16 * (slot ^ (qrow & 7)));
#pragma unroll
        for (int ni = 0; ni < 16; ++ni) {
          int krow = ni * 16 + (lane & 15);
          bf16x8 kf = *(const bf16x8*)((char*)Ks + krow * 128 + 16 * (slot ^ (krow & 7)));
          acc[ni] = __builtin_amdgcn_mfma_f32_16x16x32_bf16(qf, kf, acc[ni], 0, 0, 0);
        }
      }
      __syncthreads();
    }
#pragma unroll
    for (int r = 0; r < 4; ++r) {
      float mx = -1e30f;
#pragma unroll
      for (int ni = 0; ni < 16; ++ni) mx = fmaxf(mx, acc[ni][r]);
#pragma unroll
      for (int off = 1; off < 16; off <<= 1) mx = fmaxf(mx, __shfl_xor(mx, off, 64));
      float s = 0.0f;
#pragma unroll
      for (int ni = 0; ni < 16; ++ni) {
        float p = __expf((acc[ni][r] - mx) * sc);
        acc[ni][r] = p;
        s += p;
      }
#pragma unroll
      for (int off = 1; off < 16; off <<= 1) s += __shfl_xor(s, off, 64);
      float f = invNS / s;
#pragma unroll
      for (int ni = 0; ni < 16; ++ni) avg[ni][r] += acc[ni][r] * f;
    }
  }
  unsigned short* Of = Aout + (((long)b * 4 + m0idx) * 256 + t) * 64;
#pragma unroll
  for (int r = 0; r < 4; ++r) {
    ushort8 lo, hi;
#pragma unroll
    for (int j = 0; j < 8; ++j) { lo[j] = f2bf(avg[j][r]); hi[j] = f2bf(avg[8 + j][r]); }
    *(ushort8*)(Of + r * 16) = lo;
    *(ushort8*)(Of + r * 16 + 8) = hi;
  }
}

// ------- pass B: scale1 scores + softmax + gate combine -> ATTN (row-major) ---------
__global__ void __launch_bounds__(256) scores1_gate(
    const unsigned short* __restrict__ QK1, const unsigned short* __restrict__ A2P,
    const unsigned short* __restrict__ A3P, unsigned short* __restrict__ ATTN) {
  __shared__ unsigned short Qs[64 * 64];
  __shared__ unsigned short Ks[256 * 64];
  const int bid = blockIdx.x;
  const int b = bid >> 2, m0 = (bid & 3) * 64;
  const unsigned short* base = QK1 + ((long)b << 16);
  const int t = threadIdx.x, lane = t & 63, w = t >> 6;
  const int r8 = t >> 3, sl = t & 7;
  f32x4 acc[16] = {};
  for (int kc = 0; kc < 2; ++kc) {
#pragma unroll
    for (int i = 0; i < 2; ++i) {
      int row = i * 32 + r8;
      gl2lds16(base + (long)(m0 + row) * 256 + kc * 64 + (sl ^ (row & 7)) * 8,
               (char*)Qs + i * 4096 + t * 16);
    }
#pragma unroll
    for (int i = 0; i < 8; ++i) {
      int row = i * 32 + r8;
      gl2lds16(base + (long)row * 256 + 128 + kc * 64 + (sl ^ (row & 7)) * 8,
               (char*)Ks + i * 4096 + t * 16);
    }
    __syncthreads();
#pragma unroll
    for (int kk = 0; kk < 2; ++kk) {
      const int qrow = w * 16 + (lane & 15);
      const int slot = kk * 4 + (lane >> 4);
      bf16x8 qf = *(const bf16x8*)((char*)Qs + qrow * 128 + 16 * (slot ^ (qrow & 7)));
#pragma unroll
      for (int ni = 0; ni < 16; ++ni) {
        int krow = ni * 16 + (lane & 15);
        bf16x8 kf = *(const bf16x8*)((char*)Ks + krow * 128 + 16 * (slot ^ (krow & 7)));
        acc[ni] = __builtin_amdgcn_mfma_f32_16x16x32_bf16(qf, kf, acc[ni], 0, 0, 0);
      }
    }
    __syncthreads();
  }
  const float sc = 0.088388347648318447f;
#pragma unroll
  for (int r = 0; r < 4; ++r) {
    float mx = -1e30f;
#pragma unroll
    for (int ni = 0; ni < 16; ++ni) mx = fmaxf(mx, acc[ni][r]);
#pragma unroll
    for (int off = 1; off < 16; off <<= 1) mx = fmaxf(mx, __shfl_xor(mx, off, 64));
    float s = 0.0f;
#pragma unroll
    for (int ni = 0; ni < 16; ++ni) {
      float p = __expf((acc[ni][r] - mx) * sc);
      acc[ni][r] = p;
      s += p;
    }
#pragma unroll
    for (int off = 1; off < 16; off <<= 1) s += __shfl_xor(s, off, 64);
    float inv = 1.0f / s;
    long fidx = ((long)bid * 256 + t) * 64 + r * 16;
    ushort8 a2l = *(const ushort8*)(A2P + fidx);
    ushort8 a2h = *(const ushort8*)(A2P + fidx + 8);
    ushort8 a3l = *(const ushort8*)(A3P + fidx);
    ushort8 a3h = *(const ushort8*)(A3P + fidx + 8);
    int row = m0 + w * 16 + (lane >> 4) * 4 + r;
    long roff = ((long)b << 16) + (long)row * 256 + (lane & 15);
#pragma unroll
    for (int j = 0; j < 8; ++j) {
      float A1 = acc[j][r] * inv;
      float A2 = bf2f(a2l[j]), A3 = bf2f(a3l[j]);
      float m = fmaxf(A1, fmaxf(A2, A3));
      float e1 = __expf(A1 - m), e2 = __expf(A2 - m), e3 = __expf(A3 - m);
      ATTN[roff + j * 16] = f2bf((A1 * e1 + A2 * e2 + A3 * e3) / (e1 + e2 + e3));
    }
#pragma unroll
    for (int j = 0; j < 8; ++j) {
      float A1 = acc[8 + j][r] * inv;
      float A2 = bf2f(a2h[j]), A3 = bf2f(a3h[j]);
      float m = fmaxf(A1, fmaxf(A2, A3));
      float e1 = __expf(A1 - m), e2 = __expf(A2 - m), e3 = __expf(A3 - m);
      ATTN[roff + (8 + j) * 16] = f2bf((A1 * e1 + A2 * e2 + A3 * e3) / (e1 + e2 + e3));
    }
  }
}

// ------- generic 8-wave NT GEMM: BM=256, BN=128, swizzled ---------------------------
// BIASMODE: 0 none, 1 per-col, 2 per-row. Out row-major [M][ldo].
template <int F32OUT, int BIASMODE>
__global__ void __launch_bounds__(512) gemm8(
    const unsigned short* __restrict__ A, const unsigned short* __restrict__ B,
    void* __restrict__ OutV, const float* __restrict__ bias,
    int lda, int ldb, int K, long astr, long bstr, long ostr, int ldo) {
  extern __shared__ char smem[];  // A [256][64]sw 32K, B [128][64]sw 16K
  const int t = threadIdx.x, lane = t & 63, wid = t >> 6;
  const int wmb = (wid >> 1) * 64, wnb = (wid & 1) * 64;  // 4m x 2n waves
  const int m0 = blockIdx.y * 256, n0 = blockIdx.x * 128;
  const int bz = blockIdx.z;
  const unsigned short* Ab = A + (long)bz * astr + (long)m0 * lda;
  const unsigned short* Bb = B + (long)bz * bstr + (long)n0 * ldb;
  const int srow = t >> 3, ssl = t & 7;
  f32x4 acc[4][4] = {};
  for (int k0 = 0; k0 < K; k0 += 64) {
#pragma unroll
    for (int i = 0; i < 4; ++i) {
      int row = i * 64 + srow;
      gl2lds16(Ab + (long)row * lda + k0 + (ssl ^ (row & 7)) * 8, smem + i * 8192 + t * 16);
    }
#pragma unroll
    for (int i = 0; i < 2; ++i) {
      int row = i * 64 + srow;
      gl2lds16(Bb + (long)row * ldb + k0 + (ssl ^ (row & 7)) * 8, smem + 32768 + i * 8192 + t * 16);
    }
    __syncthreads();
#pragma unroll
    for (int kk = 0; kk < 2; ++kk) {
      const int slot = kk * 4 + (lane >> 4);
      bf16x8 af[4], bfr[4];
#pragma unroll
      for (int mi = 0; mi < 4; ++mi) {
        int row = wmb + mi * 16 + (lane & 15);
        af[mi] = *(const bf16x8*)(smem + row * 128 + 16 * (slot ^ (row & 7)));
      }
#pragma unroll
      for (int ni = 0; ni < 4; ++ni) {
        int row = wnb + ni * 16 + (lane & 15);
        bfr[ni] = *(const bf16x8*)(smem + 32768 + row * 128 + 16 * (slot ^ (row & 7)));
      }
#pragma unroll
      for (int mi = 0; mi < 4; ++mi)
#pragma unroll
        for (int ni = 0; ni < 4; ++ni)
          acc[mi][ni] = __builtin_amdgcn_mfma_f32_16x16x32_bf16(af[mi], bfr[ni], acc[mi][ni], 0, 0, 0);
    }
    __syncthreads();
  }
#pragma unroll
  for (int mi = 0; mi < 4; ++mi) {
    int rowb = m0 + wmb + mi * 16 + (lane >> 4) * 4;
    float rb[4];
#pragma unroll
    for (int r = 0; r < 4; ++r) rb[r] = (BIASMODE == 2) ? bias[rowb + r] : 0.0f;
#pragma unroll
    for (int ni = 0; ni < 4; ++ni) {
      int col = n0 + wnb + ni * 16 + (lane & 15);
      float cb = (BIASMODE == 1) ? bias[col] : 0.0f;
#pragma unroll
      for (int r = 0; r < 4; ++r) {
        float v = acc[mi][ni][r] + ((BIASMODE == 2) ? rb[r] : cb);
        if constexpr (F32OUT)
          ((float*)OutV)[(long)bz * ostr + (long)(rowb + r) * ldo + col] = v;
        else
          ((unsigned short*)OutV)[(long)bz * ostr + (long)(rowb + r) * ldo + col] = f2bf(v);
      }
    }
  }
}

// ------------------------------------------------------------------------------------
extern "C" void kernel_launch(void* const* d_in, const int* in_sizes, int n_in,
                              void* d_out, int out_size, void* d_ws, size_t ws_size,
                              hipStream_t stream) {
  (void)in_sizes; (void)n_in; (void)out_size; (void)ws_size;
  const float* x   = (const float*)d_in[0];
  const float* wq1 = (const float*)d_in[1];
  const float* bq1 = (const float*)d_in[2];
  const float* wk1 = (const float*)d_in[3];
  const float* bk1 = (const float*)d_in[4];
  const float* wq2 = (const float*)d_in[5];
  const float* bq2 = (const float*)d_in[6];
  const float* wk2 = (const float*)d_in[7];
  const float* bk2 = (const float*)d_in[8];
  const float* wq3 = (const float*)d_in[9];
  const float* bq3 = (const float*)d_in[10];
  const float* wk3 = (const float*)d_in[11];
  const float* bk3 = (const float*)d_in[12];
  const float* wv  = (const float*)d_in[13];
  const float* bv  = (const float*)d_in[14];
  const float* wo  = (const float*)d_in[15];
  const float* bo  = (const float*)d_in[16];
  char* ws = (char*)d_ws;

  // workspace layout (bytes), peak 93,782,016
  unsigned short* XT   = (unsigned short*)(ws + 0);         // [64][256][512] 16.8MB
  unsigned short* WQK1 = (unsigned short*)(ws + 16777216);  // [256][512]
  unsigned short* WQK2 = (unsigned short*)(ws + 17039360);  // [256][256]
  unsigned short* WQK3 = (unsigned short*)(ws + 17170432);  // [256][128]
  unsigned short* WVT  = (unsigned short*)(ws + 17235968);  // [512][512]  wv^T
  unsigned short* WOT  = (unsigned short*)(ws + 17760256);  // [512][512]  wo^T
  unsigned short* QK1  = (unsigned short*)(ws + 18284544);  // [64][256][256]  (dead after passB)
  unsigned short* QK2  = (unsigned short*)(ws + 26673152);  // [128][256][256] (dead after passA)
  unsigned short* QK3  = (unsigned short*)(ws + 43450368);  // [256][256][256] (dead after passA)
  unsigned short* A2P  = (unsigned short*)(ws + 77004800);  // [64][4][256][64] fragment layout
  unsigned short* A3P  = (unsigned short*)(ws + 85393408);  // [64][4][256][64] fragment layout
  unsigned short* ATTN = (unsigned short*)(ws + 43450368);  // over dead QK3 head
  unsigned short* VT   = (unsigned short*)(ws + 51838976);  // [64][512][256] over dead QK3 tail
  unsigned short* AV   = (unsigned short*)(ws + 18284544);  // [64][256][512] over dead QK1/QK2

  tcast_all<<<dim3(2232), dim3(256), 0, stream>>>(
      x, wq1, wk1, wq2, wk2, wq3, wk3, wv, wo, XT, WQK1, WQK2, WQK3, WVT, WOT);

  proj_all8<<<dim3(1, 2, 448), dim3(512), 49152, stream>>>(
      XT, WQK1, WQK2, WQK3, QK1, QK2, QK3, bq1, bk1, bq2, bk2, bq3, bk3);

  scores_mean<<<dim3(512), dim3(256), 0, stream>>>(QK2, QK3, A2P, A3P);
  scores1_gate<<<dim3(256), dim3(256), 0, stream>>>(QK1, A2P, A3P, ATTN);

  // VT[b][s'][c] = sum_s wv^T[s'][s] * xT[b][c][s] + bv[s']   (row-bias)
  gemm8<0, 2><<<dim3(2, 2, 64), dim3(512), 49152, stream>>>(
      WVT, XT, VT, bv, 512, 512, 512, 0, 131072, 131072, 256);
  // AV[b][c][s'] = sum_d attn[b][c][d] * VT[b][s'][d]          (no bias)
  gemm8<0, 0><<<dim3(4, 1, 64), dim3(512), 49152, stream>>>(
      ATTN, VT, AV, nullptr, 256, 256, 256, 65536, 131072, 131072, 512);
  // out[b][p][c] = sum_s' wo^T[p][s'] * AV[b][c][s'] + bo[p]   (row-bias, fp32)
  gemm8<1, 2><<<dim3(2, 2, 64), dim3(512), 49152, stream>>>(
      WOT, AV, d_out, bo, 512, 512, 512, 0, 131072, 131072, 256);
}

// Round 7
// 126.571 us; speedup vs baseline: 1.3208x; 1.0464x over previous
//
#include <hip/hip_runtime.h>
#include <hip/hip_bf16.h>

// ChannelDeAttention: B=64,S=512,C=256,H=128,P=512
// bf16 MFMA (16x16x32), fp32 accum. 7 launches. XOR-swizzled LDS,
// 2-phase double-buffered GEMMs, all-NT chain (no transpose epilogues).

typedef __attribute__((ext_vector_type(8))) short bf16x8;
typedef __attribute__((ext_vector_type(4))) float f32x4;
typedef __attribute__((ext_vector_type(8))) unsigned short ushort8;

typedef __attribute__((address_space(1))) void* as1vp;
typedef __attribute__((address_space(3))) void* as3vp;

__device__ __forceinline__ void gl2lds16(const void* g, void* l) {
  __builtin_amdgcn_global_load_lds((as1vp)(void*)g, (as3vp)l, 16, 0, 0);
}

__device__ __forceinline__ float bf2f(unsigned short u) {
  union { unsigned int i; float f; } v; v.i = ((unsigned int)u) << 16; return v.f;
}
__device__ __forceinline__ unsigned short f2bf(float f) {
  union { float f; unsigned int i; } v; v.f = f;
  unsigned int r = v.i + 0x7FFFu + ((v.i >> 16) & 1u);
  return (unsigned short)(r >> 16);
}

// ------- all transposes (x + 8 weights) in one launch: dst[c][r] = src[r][c] --------
__global__ void __launch_bounds__(256) tcast_all(
    const float* __restrict__ x,
    const float* __restrict__ wq1, const float* __restrict__ wk1,
    const float* __restrict__ wq2, const float* __restrict__ wk2,
    const float* __restrict__ wq3, const float* __restrict__ wk3,
    const float* __restrict__ wv, const float* __restrict__ wo,
    unsigned short* __restrict__ XT,
    unsigned short* __restrict__ W1, unsigned short* __restrict__ W2,
    unsigned short* __restrict__ W3, unsigned short* __restrict__ WV,
    unsigned short* __restrict__ WO) {
  __shared__ float lds[64][65];
  const int bid = blockIdx.x;
  const float* S; unsigned short* D; int R, Cc, r0, c0, rowoff = 0;
  if (bid < 2048) {
    int bz = bid >> 5, i = bid & 31;
    S = x + (long)bz * 131072; D = XT + (long)bz * 131072;
    R = 512; Cc = 256; r0 = (i & 7) * 64; c0 = (i >> 3) * 64;
  } else {
    int wb = bid - 2048;
    if (wb < 32) {
      int m = wb >> 4, i = wb & 15;
      S = m ? wk1 : wq1; D = W1; R = 512; Cc = 128;
      r0 = (i & 7) * 64; c0 = (i >> 3) * 64; rowoff = m * 128;
    } else if (wb < 48) {
      int m = (wb - 32) >> 3, i = (wb - 32) & 7;
      S = m ? wk2 : wq2; D = W2; R = 256; Cc = 128;
      r0 = (i & 3) * 64; c0 = (i >> 2) * 64; rowoff = m * 128;
    } else if (wb < 56) {
      int m = (wb - 48) >> 2, i = (wb - 48) & 3;
      S = m ? wk3 : wq3; D = W3; R = 128; Cc = 128;
      r0 = (i & 1) * 64; c0 = (i >> 1) * 64; rowoff = m * 128;
    } else if (wb < 120) {
      int i = wb - 56; S = wv; D = WV; R = 512; Cc = 512;
      r0 = (i & 7) * 64; c0 = (i >> 3) * 64;
    } else {
      int i = wb - 120; S = wo; D = WO; R = 512; Cc = 512;
      r0 = (i & 7) * 64; c0 = (i >> 3) * 64;
    }
  }
  const int t = threadIdx.x;
  const int c = t & 63, rbase = (t >> 6) * 16;
#pragma unroll
  for (int i = 0; i < 16; ++i)
    lds[rbase + i][c] = S[(long)(r0 + rbase + i) * Cc + c0 + c];
  __syncthreads();
  const int rr = (t & 31) * 2, ccb = t >> 5;
#pragma unroll
  for (int j = 0; j < 8; ++j) {
    int cc = ccb + j * 8;
    unsigned int u0 = f2bf(lds[rr][cc]);
    unsigned int u1 = f2bf(lds[rr + 1][cc]);
    *(unsigned int*)(D + (long)(c0 + cc + rowoff) * R + r0 + rr) = u0 | (u1 << 16);
  }
}

// ------- fused Q/K projections, 8 waves, BM=128 BN=256, swizzled, double-buffered ---
// grid (1,2,448): z<64 scale1(K=512), z<192 scale2(K=256), else scale3(K=128)
__global__ void __launch_bounds__(512) proj_all8(
    const unsigned short* __restrict__ XT,
    const unsigned short* __restrict__ W1, const unsigned short* __restrict__ W2,
    const unsigned short* __restrict__ W3,
    unsigned short* __restrict__ Q1, unsigned short* __restrict__ Q2,
    unsigned short* __restrict__ Q3,
    const float* __restrict__ bq1, const float* __restrict__ bk1,
    const float* __restrict__ bq2, const float* __restrict__ bk2,
    const float* __restrict__ bq3, const float* __restrict__ bk3) {
  extern __shared__ char smem[];  // per buf: A [128][64]sw 16K + B [256][64]sw 32K
  const int z = blockIdx.z;
  const unsigned short* Ab; const unsigned short* Bw; unsigned short* O;
  const float *bq, *bk; int K;
  if (z < 64) {
    K = 512; Bw = W1; O = Q1 + (long)z * 65536; bq = bq1; bk = bk1;
    Ab = XT + (long)z * 131072;
  } else if (z < 192) {
    int u = z - 64; K = 256; Bw = W2; O = Q2 + (long)u * 65536; bq = bq2; bk = bk2;
    Ab = XT + (long)(u >> 1) * 131072 + (u & 1) * 256;
  } else {
    int u = z - 192; K = 128; Bw = W3; O = Q3 + (long)u * 65536; bq = bq3; bk = bk3;
    Ab = XT + (long)(u >> 2) * 131072 + (u & 3) * 128;
  }
  const int t = threadIdx.x, lane = t & 63, wid = t >> 6;
  const int wmb = (wid >> 2) * 64, wnb = (wid & 3) * 64;  // 2m x 4n waves
  const int m0 = blockIdx.y * 128;
  Ab += (long)m0 * 512;
  const int srow = t >> 3, ssl = t & 7;

  auto stage = [&](int buf, int k0) {
    char* s = smem + buf * 49152;
#pragma unroll
    for (int i = 0; i < 2; ++i) {
      int row = i * 64 + srow;
      gl2lds16(Ab + (long)row * 512 + k0 + (ssl ^ (row & 7)) * 8, s + i * 8192 + t * 16);
    }
#pragma unroll
    for (int i = 0; i < 4; ++i) {
      int row = i * 64 + srow;
      gl2lds16(Bw + (long)row * K + k0 + (ssl ^ (row & 7)) * 8, s + 16384 + i * 8192 + t * 16);
    }
  };

  f32x4 acc[4][4] = {};
  stage(0, 0);
  __syncthreads();
  int cur = 0;
  for (int k0 = 0; k0 < K; k0 += 64) {
    if (k0 + 64 < K) stage(cur ^ 1, k0 + 64);
    const char* s = smem + cur * 49152;
#pragma unroll
    for (int kk = 0; kk < 2; ++kk) {
      const int slot = kk * 4 + (lane >> 4);
      bf16x8 af[4], bfr[4];
#pragma unroll
      for (int mi = 0; mi < 4; ++mi) {
        int row = wmb + mi * 16 + (lane & 15);
        af[mi] = *(const bf16x8*)(s + row * 128 + 16 * (slot ^ (row & 7)));
      }
#pragma unroll
      for (int ni = 0; ni < 4; ++ni) {
        int row = wnb + ni * 16 + (lane & 15);
        bfr[ni] = *(const bf16x8*)(s + 16384 + row * 128 + 16 * (slot ^ (row & 7)));
      }
#pragma unroll
      for (int mi = 0; mi < 4; ++mi)
#pragma unroll
        for (int ni = 0; ni < 4; ++ni)
          acc[mi][ni] = __builtin_amdgcn_mfma_f32_16x16x32_bf16(af[mi], bfr[ni], acc[mi][ni], 0, 0, 0);
    }
    __syncthreads();
    cur ^= 1;
  }
#pragma unroll
  for (int ni = 0; ni < 4; ++ni) {
    int colL = wnb + ni * 16 + (lane & 15);
    float bv_ = (colL < 128) ? bq[colL] : bk[colL - 128];
#pragma unroll
    for (int mi = 0; mi < 4; ++mi) {
      int rowb = m0 + wmb + mi * 16 + (lane >> 4) * 4;
#pragma unroll
      for (int r = 0; r < 4; ++r)
        O[(long)(rowb + r) * 256 + colL] = f2bf(acc[mi][ni][r] + bv_);
    }
  }
}

// ------- pass A: scales 2+3 scores + softmax + sub-batch mean (unchanged) -----------
__global__ void __launch_bounds__(256) scores_mean(
    const unsigned short* __restrict__ QK2, const unsigned short* __restrict__ QK3,
    unsigned short* __restrict__ A2P, unsigned short* __restrict__ A3P) {
  __shared__ unsigned short Qs[64 * 64];
  __shared__ unsigned short Ks[256 * 64];
  const int bid = blockIdx.x;
  const unsigned short* QK; unsigned short* Aout; int NS, b, m0idx;
  if (bid < 256) { NS = 4; b = bid >> 2; m0idx = bid & 3; QK = QK3; Aout = A3P; }
  else { int u = bid - 256; NS = 2; b = u >> 2; m0idx = u & 3; QK = QK2; Aout = A2P; }
  const int m0 = m0idx * 64;
  const int t = threadIdx.x, lane = t & 63, w = t >> 6;
  const int r8 = t >> 3, sl = t & 7;
  const float sc = 0.088388347648318447f;
  const float invNS = 1.0f / NS;
  f32x4 avg[16] = {};
  for (int h = 0; h < NS; ++h) {
    const unsigned short* base = QK + ((long)(b * NS + h) << 16);
    f32x4 acc[16] = {};
    for (int kc = 0; kc < 2; ++kc) {
#pragma unroll
      for (int i = 0; i < 2; ++i) {
        int row = i * 32 + r8;
        gl2lds16(base + (long)(m0 + row) * 256 + kc * 64 + (sl ^ (row & 7)) * 8,
                 (char*)Qs + i * 4096 + t * 16);
      }
#pragma unroll
      for (int i = 0; i < 8; ++i) {
        int row = i * 32 + r8;
        gl2lds16(base + (long)row * 256 + 128 + kc * 64 + (sl ^ (row & 7)) * 8,
                 (char*)Ks + i * 4096 + t * 16);
      }
      __syncthreads();
#pragma unroll
      for (int kk = 0; kk < 2; ++kk) {
        const int qrow = w * 16 + (lane & 15);
        const int slot = kk * 4 + (lane >> 4);
        bf16x8 qf = *(const bf16x8*)((char*)Qs + qrow * 128 + 16 * (slot ^ (qrow & 7)));
#pragma unroll
        for (int ni = 0; ni < 16; ++ni) {
          int krow = ni * 16 + (lane & 15);
          bf16x8 kf = *(const bf16x8*)((char*)Ks + krow * 128 + 16 * (slot ^ (krow & 7)));
          acc[ni] = __builtin_amdgcn_mfma_f32_16x16x32_bf16(qf, kf, acc[ni], 0, 0, 0);
        }
      }
      __syncthreads();
    }
#pragma unroll
    for (int r = 0; r < 4; ++r) {
      float mx = -1e30f;
#pragma unroll
      for (int ni = 0; ni < 16; ++ni) mx = fmaxf(mx, acc[ni][r]);
#pragma unroll
      for (int off = 1; off < 16; off <<= 1) mx = fmaxf(mx, __shfl_xor(mx, off, 64));
      float s = 0.0f;
#pragma unroll
      for (int ni = 0; ni < 16; ++ni) {
        float p = __expf((acc[ni][r] - mx) * sc);
        acc[ni][r] = p;
        s += p;
      }
#pragma unroll
      for (int off = 1; off < 16; off <<= 1) s += __shfl_xor(s, off, 64);
      float f = invNS / s;
#pragma unroll
      for (int ni = 0; ni < 16; ++ni) avg[ni][r] += acc[ni][r] * f;
    }
  }
  unsigned short* Of = Aout + (((long)b * 4 + m0idx) * 256 + t) * 64;
#pragma unroll
  for (int r = 0; r < 4; ++r) {
    ushort8 lo, hi;
#pragma unroll
    for (int j = 0; j < 8; ++j) { lo[j] = f2bf(avg[j][r]); hi[j] = f2bf(avg[8 + j][r]); }
    *(ushort8*)(Of + r * 16) = lo;
    *(ushort8*)(Of + r * 16 + 8) = hi;
  }
}

// ------- pass B: scale1 scores + softmax + gate combine -> ATTN (unchanged) ---------
__global__ void __launch_bounds__(256) scores1_gate(
    const unsigned short* __restrict__ QK1, const unsigned short* __restrict__ A2P,
    const unsigned short* __restrict__ A3P, unsigned short* __restrict__ ATTN) {
  __shared__ unsigned short Qs[64 * 64];
  __shared__ unsigned short Ks[256 * 64];
  const int bid = blockIdx.x;
  const int b = bid >> 2, m0 = (bid & 3) * 64;
  const unsigned short* base = QK1 + ((long)b << 16);
  const int t = threadIdx.x, lane = t & 63, w = t >> 6;
  const int r8 = t >> 3, sl = t & 7;
  f32x4 acc[16] = {};
  for (int kc = 0; kc < 2; ++kc) {
#pragma unroll
    for (int i = 0; i < 2; ++i) {
      int row = i * 32 + r8;
      gl2lds16(base + (long)(m0 + row) * 256 + kc * 64 + (sl ^ (row & 7)) * 8,
               (char*)Qs + i * 4096 + t * 16);
    }
#pragma unroll
    for (int i = 0; i < 8; ++i) {
      int row = i * 32 + r8;
      gl2lds16(base + (long)row * 256 + 128 + kc * 64 + (sl ^ (row & 7)) * 8,
               (char*)Ks + i * 4096 + t * 16);
    }
    __syncthreads();
#pragma unroll
    for (int kk = 0; kk < 2; ++kk) {
      const int qrow = w * 16 + (lane & 15);
      const int slot = kk * 4 + (lane >> 4);
      bf16x8 qf = *(const bf16x8*)((char*)Qs + qrow * 128 + 16 * (slot ^ (qrow & 7)));
#pragma unroll
      for (int ni = 0; ni < 16; ++ni) {
        int krow = ni * 16 + (lane & 15);
        bf16x8 kf = *(const bf16x8*)((char*)Ks + krow * 128 + 16 * (slot ^ (krow & 7)));
        acc[ni] = __builtin_amdgcn_mfma_f32_16x16x32_bf16(qf, kf, acc[ni], 0, 0, 0);
      }
    }
    __syncthreads();
  }
  const float sc = 0.088388347648318447f;
#pragma unroll
  for (int r = 0; r < 4; ++r) {
    float mx = -1e30f;
#pragma unroll
    for (int ni = 0; ni < 16; ++ni) mx = fmaxf(mx, acc[ni][r]);
#pragma unroll
    for (int off = 1; off < 16; off <<= 1) mx = fmaxf(mx, __shfl_xor(mx, off, 64));
    float s = 0.0f;
#pragma unroll
    for (int ni = 0; ni < 16; ++ni) {
      float p = __expf((acc[ni][r] - mx) * sc);
      acc[ni][r] = p;
      s += p;
    }
#pragma unroll
    for (int off = 1; off < 16; off <<= 1) s += __shfl_xor(s, off, 64);
    float inv = 1.0f / s;
    long fidx = ((long)bid * 256 + t) * 64 + r * 16;
    ushort8 a2l = *(const ushort8*)(A2P + fidx);
    ushort8 a2h = *(const ushort8*)(A2P + fidx + 8);
    ushort8 a3l = *(const ushort8*)(A3P + fidx);
    ushort8 a3h = *(const ushort8*)(A3P + fidx + 8);
    int row = m0 + w * 16 + (lane >> 4) * 4 + r;
    long roff = ((long)b << 16) + (long)row * 256 + (lane & 15);
#pragma unroll
    for (int j = 0; j < 8; ++j) {
      float A1 = acc[j][r] * inv;
      float A2 = bf2f(a2l[j]), A3 = bf2f(a3l[j]);
      float m = fmaxf(A1, fmaxf(A2, A3));
      float e1 = __expf(A1 - m), e2 = __expf(A2 - m), e3 = __expf(A3 - m);
      ATTN[roff + j * 16] = f2bf((A1 * e1 + A2 * e2 + A3 * e3) / (e1 + e2 + e3));
    }
#pragma unroll
    for (int j = 0; j < 8; ++j) {
      float A1 = acc[8 + j][r] * inv;
      float A2 = bf2f(a2h[j]), A3 = bf2f(a3h[j]);
      float m = fmaxf(A1, fmaxf(A2, A3));
      float e1 = __expf(A1 - m), e2 = __expf(A2 - m), e3 = __expf(A3 - m);
      ATTN[roff + (8 + j) * 16] = f2bf((A1 * e1 + A2 * e2 + A3 * e3) / (e1 + e2 + e3));
    }
  }
}

// ------- 8-wave NT GEMM, double-buffered, TALL(256x128) or WIDE(128x256) ------------
// BIASMODE: 0 none, 1 per-col, 2 per-row. Out row-major [M][ldo].
template <int TALL, int F32OUT, int BIASMODE>
__global__ void __launch_bounds__(512) gemm8(
    const unsigned short* __restrict__ A, const unsigned short* __restrict__ B,
    void* __restrict__ OutV, const float* __restrict__ bias,
    int lda, int ldb, int K, long astr, long bstr, long ostr, int ldo) {
  constexpr int BM = TALL ? 256 : 128;
  constexpr int BN = TALL ? 128 : 256;
  constexpr int NA = BM / 64, NB = BN / 64;
  extern __shared__ char smem[];  // per buf 48K: A [BM][64]sw + B [BN][64]sw
  const int t = threadIdx.x, lane = t & 63, wid = t >> 6;
  const int wmb = TALL ? (wid >> 1) * 64 : (wid >> 2) * 64;
  const int wnb = TALL ? (wid & 1) * 64 : (wid & 3) * 64;
  const int m0 = blockIdx.y * BM, n0 = blockIdx.x * BN;
  const int bz = blockIdx.z;
  const unsigned short* Ab = A + (long)bz * astr + (long)m0 * lda;
  const unsigned short* Bb = B + (long)bz * bstr + (long)n0 * ldb;
  const int srow = t >> 3, ssl = t & 7;

  auto stage = [&](int buf, int k0) {
    char* s = smem + buf * 49152;
#pragma unroll
    for (int i = 0; i < NA; ++i) {
      int row = i * 64 + srow;
      gl2lds16(Ab + (long)row * lda + k0 + (ssl ^ (row & 7)) * 8, s + i * 8192 + t * 16);
    }
#pragma unroll
    for (int i = 0; i < NB; ++i) {
      int row = i * 64 + srow;
      gl2lds16(Bb + (long)row * ldb + k0 + (ssl ^ (row & 7)) * 8,
               s + NA * 8192 + i * 8192 + t * 16);
    }
  };

  f32x4 acc[4][4] = {};
  stage(0, 0);
  __syncthreads();
  int cur = 0;
  for (int k0 = 0; k0 < K; k0 += 64) {
    if (k0 + 64 < K) stage(cur ^ 1, k0 + 64);
    const char* s = smem + cur * 49152;
#pragma unroll
    for (int kk = 0; kk < 2; ++kk) {
      const int slot = kk * 4 + (lane >> 4);
      bf16x8 af[4], bfr[4];
#pragma unroll
      for (int mi = 0; mi < 4; ++mi) {
        int row = wmb + mi * 16 + (lane & 15);
        af[mi] = *(const bf16x8*)(s + row * 128 + 16 * (slot ^ (row & 7)));
      }
#pragma unroll
      for (int ni = 0; ni < 4; ++ni) {
        int row = wnb + ni * 16 + (lane & 15);
        bfr[ni] = *(const bf16x8*)(s + NA * 8192 + row * 128 + 16 * (slot ^ (row & 7)));
      }
#pragma unroll
      for (int mi = 0; mi < 4; ++mi)
#pragma unroll
        for (int ni = 0; ni < 4; ++ni)
          acc[mi][ni] = __builtin_amdgcn_mfma_f32_16x16x32_bf16(af[mi], bfr[ni], acc[mi][ni], 0, 0, 0);
    }
    __syncthreads();
    cur ^= 1;
  }
#pragma unroll
  for (int mi = 0; mi < 4; ++mi) {
    int rowb = m0 + wmb + mi * 16 + (lane >> 4) * 4;
    float rb[4];
#pragma unroll
    for (int r = 0; r < 4; ++r) rb[r] = (BIASMODE == 2) ? bias[rowb + r] : 0.0f;
#pragma unroll
    for (int ni = 0; ni < 4; ++ni) {
      int col = n0 + wnb + ni * 16 + (lane & 15);
      float cb = (BIASMODE == 1) ? bias[col] : 0.0f;
#pragma unroll
      for (int r = 0; r < 4; ++r) {
        float v = acc[mi][ni][r] + ((BIASMODE == 2) ? rb[r] : cb);
        if constexpr (F32OUT)
          ((float*)OutV)[(long)bz * ostr + (long)(rowb + r) * ldo + col] = v;
        else
          ((unsigned short*)OutV)[(long)bz * ostr + (long)(rowb + r) * ldo + col] = f2bf(v);
      }
    }
  }
}

// ------------------------------------------------------------------------------------
extern "C" void kernel_launch(void* const* d_in, const int* in_sizes, int n_in,
                              void* d_out, int out_size, void* d_ws, size_t ws_size,
                              hipStream_t stream) {
  (void)in_sizes; (void)n_in; (void)out_size; (void)ws_size;
  const float* x   = (const float*)d_in[0];
  const float* wq1 = (const float*)d_in[1];
  const float* bq1 = (const float*)d_in[2];
  const float* wk1 = (const float*)d_in[3];
  const float* bk1 = (const float*)d_in[4];
  const float* wq2 = (const float*)d_in[5];
  const float* bq2 = (const float*)d_in[6];
  const float* wk2 = (const float*)d_in[7];
  const float* bk2 = (const float*)d_in[8];
  const float* wq3 = (const float*)d_in[9];
  const float* bq3 = (const float*)d_in[10];
  const float* wk3 = (const float*)d_in[11];
  const float* bk3 = (const float*)d_in[12];
  const float* wv  = (const float*)d_in[13];
  const float* bv  = (const float*)d_in[14];
  const float* wo  = (const float*)d_in[15];
  const float* bo  = (const float*)d_in[16];
  char* ws = (char*)d_ws;

  // workspace layout (bytes), peak 93,782,016
  unsigned short* XT   = (unsigned short*)(ws + 0);         // [64][256][512] 16.8MB
  unsigned short* WQK1 = (unsigned short*)(ws + 16777216);  // [256][512]
  unsigned short* WQK2 = (unsigned short*)(ws + 17039360);  // [256][256]
  unsigned short* WQK3 = (unsigned short*)(ws + 17170432);  // [256][128]
  unsigned short* WVT  = (unsigned short*)(ws + 17235968);  // [512][512] wv^T
  unsigned short* WOT  = (unsigned short*)(ws + 17760256);  // [512][512] wo^T
  unsigned short* QK1  = (unsigned short*)(ws + 18284544);  // [64][256][256]  (dead after passB)
  unsigned short* QK2  = (unsigned short*)(ws + 26673152);  // [128][256][256] (dead after passA)
  unsigned short* QK3  = (unsigned short*)(ws + 43450368);  // [256][256][256] (dead after passA)
  unsigned short* A2P  = (unsigned short*)(ws + 77004800);  // fragment layout (dead after passB)
  unsigned short* A3P  = (unsigned short*)(ws + 85393408);  // fragment layout (dead after passB)
  unsigned short* ATTN = (unsigned short*)(ws + 43450368);  // [64][256][256] over dead QK3 head
  unsigned short* V2   = (unsigned short*)(ws + 51838976);  // [64][256][512] over dead QK3 tail+A2P/A3P... (after passB)
  unsigned short* W2V  = (unsigned short*)(ws + 18284544);  // [64][512][256] over dead QK1/QK2

  tcast_all<<<dim3(2232), dim3(256), 0, stream>>>(
      x, wq1, wk1, wq2, wk2, wq3, wk3, wv, wo, XT, WQK1, WQK2, WQK3, WVT, WOT);

  proj_all8<<<dim3(1, 2, 448), dim3(512), 98304, stream>>>(
      XT, WQK1, WQK2, WQK3, QK1, QK2, QK3, bq1, bk1, bq2, bk2, bq3, bk3);

  scores_mean<<<dim3(512), dim3(256), 0, stream>>>(QK2, QK3, A2P, A3P);
  scores1_gate<<<dim3(256), dim3(256), 0, stream>>>(QK1, A2P, A3P, ATTN);

  // V2[b][c][s'] = sum_s XT[b][c][s]*WVT[s'][s] + bv[s']   (WIDE, col-bias)
  gemm8<0, 0, 1><<<dim3(2, 2, 64), dim3(512), 98304, stream>>>(
      XT, WVT, V2, bv, 512, 512, 512, 131072, 0, 131072, 512);
  // W2V[b][p][d] = sum_s' WOT[p][s']*V2[b][d][s']           (TALL, no bias)
  gemm8<1, 0, 0><<<dim3(2, 2, 64), dim3(512), 98304, stream>>>(
      WOT, V2, W2V, nullptr, 512, 512, 512, 0, 131072, 131072, 256);
  // out[b][p][c] = sum_d W2V[b][p][d]*ATTN[b][c][d] + bo[p] (TALL, row-bias, fp32)
  gemm8<1, 1, 2><<<dim3(2, 2, 64), dim3(512), 98304, stream>>>(
      W2V, ATTN, d_out, bo, 256, 256, 256, 131072, 65536, 131072, 256);
}